// Round 1
// baseline (1546.823 us; speedup 1.0000x reference)
//
#include <hip/hip_runtime.h>
#include <math.h>

#define NUM_GRAPHS 64
#define D 128

// ---------------- CSR build ----------------

__global__ void k_histo(const int* __restrict__ dst, int* __restrict__ deg, int E) {
    int e = blockIdx.x * blockDim.x + threadIdx.x;
    if (e < E) atomicAdd(&deg[dst[e]], 1);
}

__global__ void k_scan_block(const int* __restrict__ deg, int* __restrict__ row_ptr,
                             int* __restrict__ bsums, int N) {
    __shared__ int sm[256];
    int t = threadIdx.x;
    int i = blockIdx.x * 256 + t;
    int v = (i < N) ? deg[i] : 0;
    sm[t] = v;
    __syncthreads();
    for (int off = 1; off < 256; off <<= 1) {
        int y = (t >= off) ? sm[t - off] : 0;
        __syncthreads();
        sm[t] += y;
        __syncthreads();
    }
    if (i < N) row_ptr[i] = sm[t] - v;          // exclusive
    if (t == 255) bsums[blockIdx.x] = sm[255];  // block total
}

__global__ void k_scan_sums(int* __restrict__ bsums, int nb) {
    __shared__ int sm[512];
    int t = threadIdx.x;
    int v = (t < nb) ? bsums[t] : 0;
    sm[t] = v;
    __syncthreads();
    for (int off = 1; off < 512; off <<= 1) {
        int y = (t >= off) ? sm[t - off] : 0;
        __syncthreads();
        sm[t] += y;
        __syncthreads();
    }
    if (t < nb) bsums[t] = sm[t] - v;           // exclusive block offsets
}

__global__ void k_scan_add(int* __restrict__ row_ptr, const int* __restrict__ bsums,
                           int N, int E) {
    int i = blockIdx.x * 256 + threadIdx.x;
    if (i < N) row_ptr[i] += bsums[blockIdx.x];
    if (i == 0) row_ptr[N] = E;
}

__global__ void k_fill(const int* __restrict__ src, const int* __restrict__ dst,
                       const int* __restrict__ row_ptr, int* __restrict__ cnt,
                       int* __restrict__ csr_src, int E) {
    int e = blockIdx.x * blockDim.x + threadIdx.x;
    if (e < E) {
        int d = dst[e];
        int p = row_ptr[d] + atomicAdd(&cnt[d], 1);
        csr_src[p] = src[e];
    }
}

// ---------------- GEMM: Y[N,128] = X[N,128] @ W[128,128] ----------------

__global__ __launch_bounds__(256) void k_gemm128(const float* __restrict__ X,
                                                 const float* __restrict__ W,
                                                 float* __restrict__ Y, int N) {
    __shared__ float As[64][17];
    __shared__ float Bs[16][64];
    int tx = threadIdx.x % 16, ty = threadIdx.x / 16;
    int row0 = blockIdx.x * 64;
    int col0 = blockIdx.y * 64;
    float acc[4][4] = {};
    for (int k0 = 0; k0 < 128; k0 += 16) {
        {
            int i = threadIdx.x * 4;
            int r = i / 16, c = i % 16;
            int gr = row0 + r;
            float4 v = (gr < N) ? *(const float4*)&X[(size_t)gr * D + k0 + c]
                                : make_float4(0.f, 0.f, 0.f, 0.f);
            As[r][c] = v.x; As[r][c + 1] = v.y; As[r][c + 2] = v.z; As[r][c + 3] = v.w;
            int br = i / 64, bc = i % 64;
            float4 w = *(const float4*)&W[(size_t)(k0 + br) * D + col0 + bc];
            Bs[br][bc] = w.x; Bs[br][bc + 1] = w.y; Bs[br][bc + 2] = w.z; Bs[br][bc + 3] = w.w;
        }
        __syncthreads();
        #pragma unroll
        for (int kk = 0; kk < 16; ++kk) {
            float a[4], b[4];
            #pragma unroll
            for (int i = 0; i < 4; i++) a[i] = As[ty * 4 + i][kk];
            #pragma unroll
            for (int j = 0; j < 4; j++) b[j] = Bs[kk][tx * 4 + j];
            #pragma unroll
            for (int i = 0; i < 4; i++)
                #pragma unroll
                for (int j = 0; j < 4; j++) acc[i][j] += a[i] * b[j];
        }
        __syncthreads();
    }
    #pragma unroll
    for (int i = 0; i < 4; i++) {
        int gr = row0 + ty * 4 + i;
        if (gr < N) {
            float4 v = make_float4(acc[i][0], acc[i][1], acc[i][2], acc[i][3]);
            *(float4*)&Y[(size_t)gr * D + col0 + tx * 4] = v;
        }
    }
}

// ---------------- el/er: per-node dot with attention vectors ----------------

__global__ __launch_bounds__(256) void k_eler(const float* __restrict__ feat,
                                              const float* __restrict__ al,
                                              const float* __restrict__ ar,
                                              float* __restrict__ el,
                                              float* __restrict__ er, int N) {
    int wid = (blockIdx.x * blockDim.x + threadIdx.x) >> 6;
    int lane = threadIdx.x & 63;
    if (wid >= N) return;
    float2 f = ((const float2*)(feat + (size_t)wid * D))[lane];
    float2 a = ((const float2*)al)[lane];
    float2 r = ((const float2*)ar)[lane];
    float sl = f.x * a.x + f.y * a.y;
    float sr = f.x * r.x + f.y * r.y;
    #pragma unroll
    for (int o = 32; o >= 1; o >>= 1) {
        sl += __shfl_xor(sl, o);
        sr += __shfl_xor(sr, o);
    }
    if (lane == 0) { el[wid] = sl; er[wid] = sr; }
}

// ---------------- fused edge-softmax + aggregation + bias + relu ----------------

__global__ __launch_bounds__(256) void k_aggregate(const float* __restrict__ feat,
                                                   const float* __restrict__ el,
                                                   const float* __restrict__ er,
                                                   const int* __restrict__ row_ptr,
                                                   const int* __restrict__ csr_src,
                                                   const float* __restrict__ bias,
                                                   float* __restrict__ out, int N) {
    int wid = (blockIdx.x * blockDim.x + threadIdx.x) >> 6;
    int lane = threadIdx.x & 63;
    if (wid >= N) return;
    int beg = row_ptr[wid], end = row_ptr[wid + 1];
    int deg = end - beg;
    float erd = er[wid];

    float m = -INFINITY;
    for (int j = lane; j < deg; j += 64) {
        float e = el[csr_src[beg + j]] + erd;
        e = e >= 0.f ? e : 0.2f * e;
        m = fmaxf(m, e);
    }
    #pragma unroll
    for (int o = 32; o >= 1; o >>= 1) m = fmaxf(m, __shfl_xor(m, o));

    float s = 0.f;
    for (int j = lane; j < deg; j += 64) {
        float e = el[csr_src[beg + j]] + erd;
        e = e >= 0.f ? e : 0.2f * e;
        s += __expf(e - m);
    }
    #pragma unroll
    for (int o = 32; o >= 1; o >>= 1) s += __shfl_xor(s, o);
    float inv = (deg > 0) ? 1.f / s : 0.f;

    float2 acc = make_float2(0.f, 0.f);
    for (int j = 0; j < deg; ++j) {
        int sn = csr_src[beg + j];
        float e = el[sn] + erd;
        e = e >= 0.f ? e : 0.2f * e;
        float w = __expf(e - m) * inv;
        float2 f = ((const float2*)(feat + (size_t)sn * D))[lane];
        acc.x += w * f.x;
        acc.y += w * f.y;
    }
    float2 b = ((const float2*)bias)[lane];
    float2 o2 = make_float2(fmaxf(acc.x + b.x, 0.f), fmaxf(acc.y + b.y, 0.f));
    ((float2*)(out + (size_t)wid * D))[lane] = o2;
}

// ---------------- pooling ----------------

__global__ void k_bounds(const int* __restrict__ gid, int* __restrict__ gs,
                         int* __restrict__ ge, int N) {
    int n = blockIdx.x * blockDim.x + threadIdx.x;
    if (n < N) {
        int g = gid[n];
        atomicMin(&gs[g], n);
        atomicMax(&ge[g], n);
    }
}

__global__ __launch_bounds__(256) void k_pool(const float* __restrict__ x,
                                              const int* __restrict__ gs,
                                              const int* __restrict__ ge,
                                              float* __restrict__ hg) {
    int g = blockIdx.x;
    int start = gs[g];
    int last = ge[g];
    int t = threadIdx.x;
    int ch = t & 127, half = t >> 7;
    float acc = 0.f;
    int count = 0;
    if (start <= last) {
        count = last - start + 1;
        int endi = last + 1;
        for (int n = start + half; n < endi; n += 2)
            acc += x[(size_t)n * D + ch];
    }
    __shared__ float tmp[128];
    if (half == 1) tmp[ch] = acc;
    __syncthreads();
    if (half == 0) {
        acc += tmp[ch];
        float c = count > 0 ? (float)count : 1.f;
        hg[g * D + ch] = acc / c;
    }
}

__global__ void k_final(const float* __restrict__ hg, const float* __restrict__ Wfc,
                        const float* __restrict__ bfc, float* __restrict__ out) {
    int g = threadIdx.x;
    if (g >= NUM_GRAPHS) return;
    float l0 = bfc[0], l1 = bfc[1];
    for (int d = 0; d < D; d++) {
        float v = hg[g * D + d];
        l0 += v * Wfc[2 * d];
        l1 += v * Wfc[2 * d + 1];
    }
    float mm = fmaxf(l0, l1);
    float lse = mm + logf(expf(l0 - mm) + expf(l1 - mm));
    out[2 * g] = l0 - lse;
    out[2 * g + 1] = l1 - lse;
}

// ---------------- launch ----------------

extern "C" void kernel_launch(void* const* d_in, const int* in_sizes, int n_in,
                              void* d_out, int out_size, void* d_ws, size_t ws_size,
                              hipStream_t stream) {
    const float* h   = (const float*)d_in[0];
    const int* src   = (const int*)d_in[1];
    const int* dst   = (const int*)d_in[2];
    const int* gid   = (const int*)d_in[3];
    const float* W1  = (const float*)d_in[4];
    const float* al1 = (const float*)d_in[5];
    const float* ar1 = (const float*)d_in[6];
    const float* b1  = (const float*)d_in[7];
    const float* W2  = (const float*)d_in[8];
    const float* al2 = (const float*)d_in[9];
    const float* ar2 = (const float*)d_in[10];
    const float* b2  = (const float*)d_in[11];
    const float* Wfc = (const float*)d_in[12];
    const float* bfc = (const float*)d_in[13];
    float* out = (float*)d_out;

    int N = in_sizes[0] / D;
    int E = in_sizes[1];

    char* p = (char*)d_ws;
    float* featA = (float*)p; p += (size_t)N * D * 4;
    float* featB = (float*)p; p += (size_t)N * D * 4;
    float* el    = (float*)p; p += (size_t)N * 4;
    float* er    = (float*)p; p += (size_t)N * 4;
    int* row_ptr = (int*)p;   p += (size_t)(N + 1) * 4;
    int* deg     = (int*)p;   p += (size_t)N * 4;
    int* cnt     = (int*)p;   p += (size_t)N * 4;
    int* csr_src = (int*)p;   p += (size_t)E * 4;
    int* bsums   = (int*)p;   p += 1024 * 4;
    int* gs      = (int*)p;   p += NUM_GRAPHS * 4;
    int* ge      = (int*)p;   p += NUM_GRAPHS * 4;
    float* hg    = (float*)p; p += NUM_GRAPHS * D * 4;

    int nbN = (N + 255) / 256;
    int nbE = (E + 255) / 256;
    int nbW = (N * 64 + 255) / 256;  // wave-per-node grids

    hipMemsetAsync(deg, 0, (size_t)N * 4, stream);
    hipMemsetAsync(cnt, 0, (size_t)N * 4, stream);
    hipMemsetAsync(gs, 0x7f, NUM_GRAPHS * 4, stream);
    hipMemsetAsync(ge, 0, NUM_GRAPHS * 4, stream);

    // CSR build (shared by both layers)
    k_histo<<<nbE, 256, 0, stream>>>(dst, deg, E);
    k_scan_block<<<nbN, 256, 0, stream>>>(deg, row_ptr, bsums, N);
    k_scan_sums<<<1, 512, 0, stream>>>(bsums, nbN);
    k_scan_add<<<nbN, 256, 0, stream>>>(row_ptr, bsums, N, E);
    k_fill<<<nbE, 256, 0, stream>>>(src, dst, row_ptr, cnt, csr_src, E);

    dim3 ggrid((N + 63) / 64, 2);

    // Layer 1
    k_gemm128<<<ggrid, 256, 0, stream>>>(h, W1, featA, N);
    k_eler<<<nbW, 256, 0, stream>>>(featA, al1, ar1, el, er, N);
    k_aggregate<<<nbW, 256, 0, stream>>>(featA, el, er, row_ptr, csr_src, b1, featB, N);

    // Layer 2
    k_gemm128<<<ggrid, 256, 0, stream>>>(featB, W2, featA, N);
    k_eler<<<nbW, 256, 0, stream>>>(featA, al2, ar2, el, er, N);
    k_aggregate<<<nbW, 256, 0, stream>>>(featA, el, er, row_ptr, csr_src, b2, featB, N);

    // Pool + FC + log_softmax
    k_bounds<<<nbN, 256, 0, stream>>>(gid, gs, ge, N);
    k_pool<<<NUM_GRAPHS, 256, 0, stream>>>(featB, gs, ge, hg);
    k_final<<<1, 64, 0, stream>>>(hg, Wfc, bfc, out);
}

// Round 2
// 993.058 us; speedup vs baseline: 1.5576x; 1.5576x over previous
//
#include <hip/hip_runtime.h>
#include <math.h>

#define NUM_GRAPHS 64
#define D 128

// ---------------- CSR build ----------------

__global__ void k_histo(const int* __restrict__ dst, int* __restrict__ deg, int E) {
    int e = blockIdx.x * blockDim.x + threadIdx.x;
    if (e < E) atomicAdd(&deg[dst[e]], 1);
}

__global__ void k_scan_block(const int* __restrict__ deg, int* __restrict__ row_ptr,
                             int* __restrict__ bsums, int N) {
    __shared__ int sm[256];
    int t = threadIdx.x;
    int i = blockIdx.x * 256 + t;
    int v = (i < N) ? deg[i] : 0;
    sm[t] = v;
    __syncthreads();
    for (int off = 1; off < 256; off <<= 1) {
        int y = (t >= off) ? sm[t - off] : 0;
        __syncthreads();
        sm[t] += y;
        __syncthreads();
    }
    if (i < N) row_ptr[i] = sm[t] - v;          // exclusive
    if (t == 255) bsums[blockIdx.x] = sm[255];  // block total
}

__global__ void k_scan_sums(int* __restrict__ bsums, int nb) {
    __shared__ int sm[512];
    int t = threadIdx.x;
    int v = (t < nb) ? bsums[t] : 0;
    sm[t] = v;
    __syncthreads();
    for (int off = 1; off < 512; off <<= 1) {
        int y = (t >= off) ? sm[t - off] : 0;
        __syncthreads();
        sm[t] += y;
        __syncthreads();
    }
    if (t < nb) bsums[t] = sm[t] - v;           // exclusive block offsets
}

__global__ void k_scan_add(int* __restrict__ row_ptr, const int* __restrict__ bsums,
                           int N, int E) {
    int i = blockIdx.x * 256 + threadIdx.x;
    if (i < N) row_ptr[i] += bsums[blockIdx.x];
    if (i == 0) row_ptr[N] = E;
}

__global__ void k_fill(const int* __restrict__ src, const int* __restrict__ dst,
                       const int* __restrict__ row_ptr, int* __restrict__ cnt,
                       int* __restrict__ csr_src, int E) {
    int e = blockIdx.x * blockDim.x + threadIdx.x;
    if (e < E) {
        int d = dst[e];
        int p = row_ptr[d] + atomicAdd(&cnt[d], 1);
        csr_src[p] = src[e];
    }
}

// ---------------- GEMM: Y[N,128] = X[N,128] @ W[128,128] ----------------

__global__ __launch_bounds__(256) void k_gemm128(const float* __restrict__ X,
                                                 const float* __restrict__ W,
                                                 float* __restrict__ Y, int N) {
    __shared__ float As[64][17];
    __shared__ float Bs[16][64];
    int tx = threadIdx.x % 16, ty = threadIdx.x / 16;
    int row0 = blockIdx.x * 64;
    int col0 = blockIdx.y * 64;
    float acc[4][4] = {};
    for (int k0 = 0; k0 < 128; k0 += 16) {
        {
            int i = threadIdx.x * 4;
            int r = i / 16, c = i % 16;
            int gr = row0 + r;
            float4 v = (gr < N) ? *(const float4*)&X[(size_t)gr * D + k0 + c]
                                : make_float4(0.f, 0.f, 0.f, 0.f);
            As[r][c] = v.x; As[r][c + 1] = v.y; As[r][c + 2] = v.z; As[r][c + 3] = v.w;
            int br = i / 64, bc = i % 64;
            float4 w = *(const float4*)&W[(size_t)(k0 + br) * D + col0 + bc];
            Bs[br][bc] = w.x; Bs[br][bc + 1] = w.y; Bs[br][bc + 2] = w.z; Bs[br][bc + 3] = w.w;
        }
        __syncthreads();
        #pragma unroll
        for (int kk = 0; kk < 16; ++kk) {
            float a[4], b[4];
            #pragma unroll
            for (int i = 0; i < 4; i++) a[i] = As[ty * 4 + i][kk];
            #pragma unroll
            for (int j = 0; j < 4; j++) b[j] = Bs[kk][tx * 4 + j];
            #pragma unroll
            for (int i = 0; i < 4; i++)
                #pragma unroll
                for (int j = 0; j < 4; j++) acc[i][j] += a[i] * b[j];
        }
        __syncthreads();
    }
    #pragma unroll
    for (int i = 0; i < 4; i++) {
        int gr = row0 + ty * 4 + i;
        if (gr < N) {
            float4 v = make_float4(acc[i][0], acc[i][1], acc[i][2], acc[i][3]);
            *(float4*)&Y[(size_t)gr * D + col0 + tx * 4] = v;
        }
    }
}

// ---------------- el/er: per-node dot with attention vectors ----------------

__global__ __launch_bounds__(256) void k_eler(const float* __restrict__ feat,
                                              const float* __restrict__ al,
                                              const float* __restrict__ ar,
                                              float* __restrict__ el,
                                              float* __restrict__ er, int N) {
    int wid = (blockIdx.x * blockDim.x + threadIdx.x) >> 6;
    int lane = threadIdx.x & 63;
    if (wid >= N) return;
    float2 f = ((const float2*)(feat + (size_t)wid * D))[lane];
    float2 a = ((const float2*)al)[lane];
    float2 r = ((const float2*)ar)[lane];
    float sl = f.x * a.x + f.y * a.y;
    float sr = f.x * r.x + f.y * r.y;
    #pragma unroll
    for (int o = 32; o >= 1; o >>= 1) {
        sl += __shfl_xor(sl, o);
        sr += __shfl_xor(sr, o);
    }
    if (lane == 0) { el[wid] = sl; er[wid] = sr; }
}

// ---------------- fused edge-softmax + aggregation + bias + relu ----------------

__global__ __launch_bounds__(256) void k_aggregate(const float* __restrict__ feat,
                                                   const float* __restrict__ el,
                                                   const float* __restrict__ er,
                                                   const int* __restrict__ row_ptr,
                                                   const int* __restrict__ csr_src,
                                                   const float* __restrict__ bias,
                                                   float* __restrict__ out, int N) {
    int wid = (blockIdx.x * blockDim.x + threadIdx.x) >> 6;
    int lane = threadIdx.x & 63;
    if (wid >= N) return;
    int beg = row_ptr[wid], end = row_ptr[wid + 1];
    int deg = end - beg;
    float erd = er[wid];

    float m = -INFINITY;
    for (int j = lane; j < deg; j += 64) {
        float e = el[csr_src[beg + j]] + erd;
        e = e >= 0.f ? e : 0.2f * e;
        m = fmaxf(m, e);
    }
    #pragma unroll
    for (int o = 32; o >= 1; o >>= 1) m = fmaxf(m, __shfl_xor(m, o));

    float s = 0.f;
    for (int j = lane; j < deg; j += 64) {
        float e = el[csr_src[beg + j]] + erd;
        e = e >= 0.f ? e : 0.2f * e;
        s += __expf(e - m);
    }
    #pragma unroll
    for (int o = 32; o >= 1; o >>= 1) s += __shfl_xor(s, o);
    float inv = (deg > 0) ? 1.f / s : 0.f;

    float2 acc = make_float2(0.f, 0.f);
    for (int j = 0; j < deg; ++j) {
        int sn = csr_src[beg + j];
        float e = el[sn] + erd;
        e = e >= 0.f ? e : 0.2f * e;
        float w = __expf(e - m) * inv;
        float2 f = ((const float2*)(feat + (size_t)sn * D))[lane];
        acc.x += w * f.x;
        acc.y += w * f.y;
    }
    float2 b = ((const float2*)bias)[lane];
    float2 o2 = make_float2(fmaxf(acc.x + b.x, 0.f), fmaxf(acc.y + b.y, 0.f));
    ((float2*)(out + (size_t)wid * D))[lane] = o2;
}

// ---------------- pooling ----------------

// graph_id is sorted -> per-graph ranges are contiguous; find boundaries with
// plain stores (the atomicMin/Max version serialized 200K RMWs on 64 words
// and cost ~575 us).
__global__ void k_bounds_sorted(const int* __restrict__ gid, int* __restrict__ gs,
                                int* __restrict__ ge, int N) {
    int n = blockIdx.x * blockDim.x + threadIdx.x;
    if (n >= N) return;
    int g = gid[n];
    if (n == 0 || gid[n - 1] != g) gs[g] = n;
    if (n == N - 1 || gid[n + 1] != g) ge[g] = n;
}

__global__ __launch_bounds__(256) void k_pool(const float* __restrict__ x,
                                              const int* __restrict__ gs,
                                              const int* __restrict__ ge,
                                              float* __restrict__ hg) {
    int g = blockIdx.x;
    int start = gs[g];
    int last = ge[g];
    int t = threadIdx.x;
    int ch = t & 127, half = t >> 7;
    float acc = 0.f;
    int count = 0;
    if (start <= last) {
        count = last - start + 1;
        int endi = last + 1;
        for (int n = start + half; n < endi; n += 2)
            acc += x[(size_t)n * D + ch];
    }
    __shared__ float tmp[128];
    if (half == 1) tmp[ch] = acc;
    __syncthreads();
    if (half == 0) {
        acc += tmp[ch];
        float c = count > 0 ? (float)count : 1.f;
        hg[g * D + ch] = acc / c;
    }
}

__global__ void k_final(const float* __restrict__ hg, const float* __restrict__ Wfc,
                        const float* __restrict__ bfc, float* __restrict__ out) {
    int g = threadIdx.x;
    if (g >= NUM_GRAPHS) return;
    float l0 = bfc[0], l1 = bfc[1];
    for (int d = 0; d < D; d++) {
        float v = hg[g * D + d];
        l0 += v * Wfc[2 * d];
        l1 += v * Wfc[2 * d + 1];
    }
    float mm = fmaxf(l0, l1);
    float lse = mm + logf(expf(l0 - mm) + expf(l1 - mm));
    out[2 * g] = l0 - lse;
    out[2 * g + 1] = l1 - lse;
}

// ---------------- launch ----------------

extern "C" void kernel_launch(void* const* d_in, const int* in_sizes, int n_in,
                              void* d_out, int out_size, void* d_ws, size_t ws_size,
                              hipStream_t stream) {
    const float* h   = (const float*)d_in[0];
    const int* src   = (const int*)d_in[1];
    const int* dst   = (const int*)d_in[2];
    const int* gid   = (const int*)d_in[3];
    const float* W1  = (const float*)d_in[4];
    const float* al1 = (const float*)d_in[5];
    const float* ar1 = (const float*)d_in[6];
    const float* b1  = (const float*)d_in[7];
    const float* W2  = (const float*)d_in[8];
    const float* al2 = (const float*)d_in[9];
    const float* ar2 = (const float*)d_in[10];
    const float* b2  = (const float*)d_in[11];
    const float* Wfc = (const float*)d_in[12];
    const float* bfc = (const float*)d_in[13];
    float* out = (float*)d_out;

    int N = in_sizes[0] / D;
    int E = in_sizes[1];

    char* p = (char*)d_ws;
    float* featA = (float*)p; p += (size_t)N * D * 4;
    float* featB = (float*)p; p += (size_t)N * D * 4;
    float* el    = (float*)p; p += (size_t)N * 4;
    float* er    = (float*)p; p += (size_t)N * 4;
    int* row_ptr = (int*)p;   p += (size_t)(N + 1) * 4;
    int* deg     = (int*)p;   p += (size_t)N * 4;
    int* cnt     = (int*)p;   p += (size_t)N * 4;
    int* csr_src = (int*)p;   p += (size_t)E * 4;
    int* bsums   = (int*)p;   p += 1024 * 4;
    int* gs      = (int*)p;   p += NUM_GRAPHS * 4;
    int* ge      = (int*)p;   p += NUM_GRAPHS * 4;
    float* hg    = (float*)p; p += NUM_GRAPHS * D * 4;

    int nbN = (N + 255) / 256;
    int nbE = (E + 255) / 256;
    int nbW = (N * 64 + 255) / 256;  // wave-per-node grids

    hipMemsetAsync(deg, 0, (size_t)N * 4, stream);
    hipMemsetAsync(cnt, 0, (size_t)N * 4, stream);
    hipMemsetAsync(gs, 0x7f, NUM_GRAPHS * 4, stream);  // +huge
    hipMemsetAsync(ge, 0xff, NUM_GRAPHS * 4, stream);  // -1

    // CSR build (shared by both layers)
    k_histo<<<nbE, 256, 0, stream>>>(dst, deg, E);
    k_scan_block<<<nbN, 256, 0, stream>>>(deg, row_ptr, bsums, N);
    k_scan_sums<<<1, 512, 0, stream>>>(bsums, nbN);
    k_scan_add<<<nbN, 256, 0, stream>>>(row_ptr, bsums, N, E);
    k_fill<<<nbE, 256, 0, stream>>>(src, dst, row_ptr, cnt, csr_src, E);

    dim3 ggrid((N + 63) / 64, 2);

    // Layer 1
    k_gemm128<<<ggrid, 256, 0, stream>>>(h, W1, featA, N);
    k_eler<<<nbW, 256, 0, stream>>>(featA, al1, ar1, el, er, N);
    k_aggregate<<<nbW, 256, 0, stream>>>(featA, el, er, row_ptr, csr_src, b1, featB, N);

    // Layer 2
    k_gemm128<<<ggrid, 256, 0, stream>>>(featB, W2, featA, N);
    k_eler<<<nbW, 256, 0, stream>>>(featA, al2, ar2, el, er, N);
    k_aggregate<<<nbW, 256, 0, stream>>>(featA, el, er, row_ptr, csr_src, b2, featB, N);

    // Pool + FC + log_softmax
    k_bounds_sorted<<<nbN, 256, 0, stream>>>(gid, gs, ge, N);
    k_pool<<<NUM_GRAPHS, 256, 0, stream>>>(featB, gs, ge, hg);
    k_final<<<1, 64, 0, stream>>>(hg, Wfc, bfc, out);
}

// Round 3
// 706.666 us; speedup vs baseline: 2.1889x; 1.4053x over previous
//
#include <hip/hip_runtime.h>
#include <math.h>

#define NUM_GRAPHS 64
#define D 128
#define PCHUNK 16

// ---------------- CSR build ----------------

__global__ void k_histo(const int* __restrict__ dst, int* __restrict__ deg, int E) {
    int e = blockIdx.x * blockDim.x + threadIdx.x;
    if (e < E) atomicAdd(&deg[dst[e]], 1);
}

__global__ void k_scan_block(const int* __restrict__ deg, int* __restrict__ row_ptr,
                             int* __restrict__ bsums, int N) {
    __shared__ int sm[256];
    int t = threadIdx.x;
    int i = blockIdx.x * 256 + t;
    int v = (i < N) ? deg[i] : 0;
    sm[t] = v;
    __syncthreads();
    for (int off = 1; off < 256; off <<= 1) {
        int y = (t >= off) ? sm[t - off] : 0;
        __syncthreads();
        sm[t] += y;
        __syncthreads();
    }
    if (i < N) row_ptr[i] = sm[t] - v;          // exclusive
    if (t == 255) bsums[blockIdx.x] = sm[255];  // block total
}

__global__ void k_scan_sums(int* __restrict__ bsums, int nb) {
    __shared__ int sm[512];
    int t = threadIdx.x;
    int v = (t < nb) ? bsums[t] : 0;
    sm[t] = v;
    __syncthreads();
    for (int off = 1; off < 512; off <<= 1) {
        int y = (t >= off) ? sm[t - off] : 0;
        __syncthreads();
        sm[t] += y;
        __syncthreads();
    }
    if (t < nb) bsums[t] = sm[t] - v;           // exclusive block offsets
}

__global__ void k_scan_add(int* __restrict__ row_ptr, const int* __restrict__ bsums,
                           int N, int E) {
    int i = blockIdx.x * 256 + threadIdx.x;
    if (i < N) row_ptr[i] += bsums[blockIdx.x];
    if (i == 0) row_ptr[N] = E;
}

__global__ void k_fill(const int* __restrict__ src, const int* __restrict__ dst,
                       const int* __restrict__ row_ptr, int* __restrict__ cnt,
                       int* __restrict__ csr_src, int E) {
    int e = blockIdx.x * blockDim.x + threadIdx.x;
    if (e < E) {
        int d = dst[e];
        int p = row_ptr[d] + atomicAdd(&cnt[d], 1);
        csr_src[p] = src[e];
    }
}

// ---------------- GEMM: Y[N,128] = X[N,128] @ W[128,128] ----------------

__global__ __launch_bounds__(256) void k_gemm128(const float* __restrict__ X,
                                                 const float* __restrict__ W,
                                                 float* __restrict__ Y, int N) {
    __shared__ float As[64][17];
    __shared__ float Bs[16][64];
    int tx = threadIdx.x % 16, ty = threadIdx.x / 16;
    int row0 = blockIdx.x * 64;
    int col0 = blockIdx.y * 64;
    float acc[4][4] = {};
    for (int k0 = 0; k0 < 128; k0 += 16) {
        {
            int i = threadIdx.x * 4;
            int r = i / 16, c = i % 16;
            int gr = row0 + r;
            float4 v = (gr < N) ? *(const float4*)&X[(size_t)gr * D + k0 + c]
                                : make_float4(0.f, 0.f, 0.f, 0.f);
            As[r][c] = v.x; As[r][c + 1] = v.y; As[r][c + 2] = v.z; As[r][c + 3] = v.w;
            int br = i / 64, bc = i % 64;
            float4 w = *(const float4*)&W[(size_t)(k0 + br) * D + col0 + bc];
            Bs[br][bc] = w.x; Bs[br][bc + 1] = w.y; Bs[br][bc + 2] = w.z; Bs[br][bc + 3] = w.w;
        }
        __syncthreads();
        #pragma unroll
        for (int kk = 0; kk < 16; ++kk) {
            float a[4], b[4];
            #pragma unroll
            for (int i = 0; i < 4; i++) a[i] = As[ty * 4 + i][kk];
            #pragma unroll
            for (int j = 0; j < 4; j++) b[j] = Bs[kk][tx * 4 + j];
            #pragma unroll
            for (int i = 0; i < 4; i++)
                #pragma unroll
                for (int j = 0; j < 4; j++) acc[i][j] += a[i] * b[j];
        }
        __syncthreads();
    }
    #pragma unroll
    for (int i = 0; i < 4; i++) {
        int gr = row0 + ty * 4 + i;
        if (gr < N) {
            float4 v = make_float4(acc[i][0], acc[i][1], acc[i][2], acc[i][3]);
            *(float4*)&Y[(size_t)gr * D + col0 + tx * 4] = v;
        }
    }
}

// ---------------- el/er: per-node dot with attention vectors ----------------

__global__ __launch_bounds__(256) void k_eler(const float* __restrict__ feat,
                                              const float* __restrict__ al,
                                              const float* __restrict__ ar,
                                              float* __restrict__ el,
                                              float* __restrict__ er, int N) {
    int wid = (blockIdx.x * blockDim.x + threadIdx.x) >> 6;
    int lane = threadIdx.x & 63;
    if (wid >= N) return;
    float2 f = ((const float2*)(feat + (size_t)wid * D))[lane];
    float2 a = ((const float2*)al)[lane];
    float2 r = ((const float2*)ar)[lane];
    float sl = f.x * a.x + f.y * a.y;
    float sr = f.x * r.x + f.y * r.y;
    #pragma unroll
    for (int o = 32; o >= 1; o >>= 1) {
        sl += __shfl_xor(sl, o);
        sr += __shfl_xor(sr, o);
    }
    if (lane == 0) { el[wid] = sl; er[wid] = sr; }
}

// ---------------- fused edge-softmax + aggregation + bias + relu ----------------
// One wave per dst node. Softmax stats lane-parallel over edges. Weighted
// gather: wave split into two 32-lane halves (float4 covers all 128 ch),
// halves take alternating edges, unrolled x4 -> 8 feature rows in flight.

__global__ __launch_bounds__(256) void k_aggregate(const float* __restrict__ feat,
                                                   const float* __restrict__ el,
                                                   const float* __restrict__ er,
                                                   const int* __restrict__ row_ptr,
                                                   const int* __restrict__ csr_src,
                                                   const float* __restrict__ bias,
                                                   float* __restrict__ out, int N) {
    int wid = (blockIdx.x * blockDim.x + threadIdx.x) >> 6;
    int lane = threadIdx.x & 63;
    if (wid >= N) return;
    int beg = row_ptr[wid], end = row_ptr[wid + 1];
    int deg = end - beg;
    float erd = er[wid];

    float m = -INFINITY;
    for (int j = lane; j < deg; j += 64) {
        float e = el[csr_src[beg + j]] + erd;
        e = e >= 0.f ? e : 0.2f * e;
        m = fmaxf(m, e);
    }
    #pragma unroll
    for (int o = 32; o >= 1; o >>= 1) m = fmaxf(m, __shfl_xor(m, o));

    float s = 0.f;
    for (int j = lane; j < deg; j += 64) {
        float e = el[csr_src[beg + j]] + erd;
        e = e >= 0.f ? e : 0.2f * e;
        s += __expf(e - m);
    }
    #pragma unroll
    for (int o = 32; o >= 1; o >>= 1) s += __shfl_xor(s, o);
    float inv = (deg > 0) ? 1.f / s : 0.f;

    int half = lane >> 5;    // 0/1: which edge parity this half-wave takes
    int sub  = lane & 31;    // channel group: floats sub*4 .. sub*4+3
    const float4* feat4 = (const float4*)feat;
    float4 acc = make_float4(0.f, 0.f, 0.f, 0.f);

    int j = beg + half;
    for (; j + 6 < end; j += 8) {   // edges j, j+2, j+4, j+6 for this half
        int sn0 = csr_src[j];
        int sn1 = csr_src[j + 2];
        int sn2 = csr_src[j + 4];
        int sn3 = csr_src[j + 6];
        float e0 = el[sn0] + erd; e0 = e0 >= 0.f ? e0 : 0.2f * e0;
        float e1 = el[sn1] + erd; e1 = e1 >= 0.f ? e1 : 0.2f * e1;
        float e2 = el[sn2] + erd; e2 = e2 >= 0.f ? e2 : 0.2f * e2;
        float e3 = el[sn3] + erd; e3 = e3 >= 0.f ? e3 : 0.2f * e3;
        float w0 = __expf(e0 - m) * inv;
        float w1 = __expf(e1 - m) * inv;
        float w2 = __expf(e2 - m) * inv;
        float w3 = __expf(e3 - m) * inv;
        float4 f0 = feat4[(size_t)sn0 * 32 + sub];
        float4 f1 = feat4[(size_t)sn1 * 32 + sub];
        float4 f2 = feat4[(size_t)sn2 * 32 + sub];
        float4 f3 = feat4[(size_t)sn3 * 32 + sub];
        acc.x += w0 * f0.x + w1 * f1.x + w2 * f2.x + w3 * f3.x;
        acc.y += w0 * f0.y + w1 * f1.y + w2 * f2.y + w3 * f3.y;
        acc.z += w0 * f0.z + w1 * f1.z + w2 * f2.z + w3 * f3.z;
        acc.w += w0 * f0.w + w1 * f1.w + w2 * f2.w + w3 * f3.w;
    }
    for (; j < end; j += 2) {
        int sn = csr_src[j];
        float e = el[sn] + erd; e = e >= 0.f ? e : 0.2f * e;
        float w = __expf(e - m) * inv;
        float4 f = feat4[(size_t)sn * 32 + sub];
        acc.x += w * f.x; acc.y += w * f.y; acc.z += w * f.z; acc.w += w * f.w;
    }
    // combine the two halves (lane i and i+32 hold same channels)
    acc.x += __shfl_xor(acc.x, 32);
    acc.y += __shfl_xor(acc.y, 32);
    acc.z += __shfl_xor(acc.z, 32);
    acc.w += __shfl_xor(acc.w, 32);

    if (half == 0) {
        float4 b = ((const float4*)bias)[sub];
        float4 o4;
        o4.x = fmaxf(acc.x + b.x, 0.f);
        o4.y = fmaxf(acc.y + b.y, 0.f);
        o4.z = fmaxf(acc.z + b.z, 0.f);
        o4.w = fmaxf(acc.w + b.w, 0.f);
        ((float4*)(out + (size_t)wid * D))[sub] = o4;
    }
}

// ---------------- pooling ----------------

// graph_id is sorted -> contiguous ranges, plain stores.
__global__ void k_bounds_sorted(const int* __restrict__ gid, int* __restrict__ gs,
                                int* __restrict__ ge, int N) {
    int n = blockIdx.x * blockDim.x + threadIdx.x;
    if (n >= N) return;
    int g = gid[n];
    if (n == 0 || gid[n - 1] != g) gs[g] = n;
    if (n == N - 1 || gid[n + 1] != g) ge[g] = n;
}

// Grid (NUM_GRAPHS, PCHUNK): 1024 blocks. Block = 8 row slots x 32 ch threads
// (float4). Partial sums -> LDS reduce -> 16-way-contended atomicAdd into hg.
__global__ __launch_bounds__(256) void k_pool_partial(const float* __restrict__ x,
                                                      const int* __restrict__ gs,
                                                      const int* __restrict__ ge,
                                                      float* __restrict__ hg) {
    int g = blockIdx.x, c = blockIdx.y;
    int start = gs[g], last = ge[g];
    if (start > last) return;
    int sub = threadIdx.x & 31;   // channel group
    int r   = threadIdx.x >> 5;   // 0..7 row slot
    const float4* x4 = (const float4*)x;
    float4 acc = make_float4(0.f, 0.f, 0.f, 0.f);
    for (int n = start + c * 8 + r; n <= last; n += PCHUNK * 8) {
        float4 v = x4[(size_t)n * 32 + sub];
        acc.x += v.x; acc.y += v.y; acc.z += v.z; acc.w += v.w;
    }
    __shared__ float4 sm[256];
    sm[threadIdx.x] = acc;
    __syncthreads();
    for (int off = 4; off >= 1; off >>= 1) {
        if (r < off) {
            float4 o = sm[threadIdx.x + off * 32];
            float4 v = sm[threadIdx.x];
            v.x += o.x; v.y += o.y; v.z += o.z; v.w += o.w;
            sm[threadIdx.x] = v;
        }
        __syncthreads();
    }
    if (r == 0) {
        float4 v = sm[sub];
        atomicAdd(&hg[g * D + sub * 4 + 0], v.x);
        atomicAdd(&hg[g * D + sub * 4 + 1], v.y);
        atomicAdd(&hg[g * D + sub * 4 + 2], v.z);
        atomicAdd(&hg[g * D + sub * 4 + 3], v.w);
    }
}

__global__ void k_final(const float* __restrict__ hg, const int* __restrict__ gs,
                        const int* __restrict__ ge, const float* __restrict__ Wfc,
                        const float* __restrict__ bfc, float* __restrict__ out) {
    int g = threadIdx.x;
    if (g >= NUM_GRAPHS) return;
    int start = gs[g], last = ge[g];
    float cnt = (start <= last) ? (float)(last - start + 1) : 1.f;
    float ic = 1.f / cnt;
    float l0 = bfc[0], l1 = bfc[1];
    for (int d = 0; d < D; d++) {
        float v = hg[g * D + d] * ic;
        l0 += v * Wfc[2 * d];
        l1 += v * Wfc[2 * d + 1];
    }
    float mm = fmaxf(l0, l1);
    float lse = mm + logf(expf(l0 - mm) + expf(l1 - mm));
    out[2 * g] = l0 - lse;
    out[2 * g + 1] = l1 - lse;
}

// ---------------- launch ----------------

extern "C" void kernel_launch(void* const* d_in, const int* in_sizes, int n_in,
                              void* d_out, int out_size, void* d_ws, size_t ws_size,
                              hipStream_t stream) {
    const float* h   = (const float*)d_in[0];
    const int* src   = (const int*)d_in[1];
    const int* dst   = (const int*)d_in[2];
    const int* gid   = (const int*)d_in[3];
    const float* W1  = (const float*)d_in[4];
    const float* al1 = (const float*)d_in[5];
    const float* ar1 = (const float*)d_in[6];
    const float* b1  = (const float*)d_in[7];
    const float* W2  = (const float*)d_in[8];
    const float* al2 = (const float*)d_in[9];
    const float* ar2 = (const float*)d_in[10];
    const float* b2  = (const float*)d_in[11];
    const float* Wfc = (const float*)d_in[12];
    const float* bfc = (const float*)d_in[13];
    float* out = (float*)d_out;

    int N = in_sizes[0] / D;
    int E = in_sizes[1];

    char* p = (char*)d_ws;
    float* featA = (float*)p; p += (size_t)N * D * 4;
    float* featB = (float*)p; p += (size_t)N * D * 4;
    float* el    = (float*)p; p += (size_t)N * 4;
    float* er    = (float*)p; p += (size_t)N * 4;
    int* row_ptr = (int*)p;   p += (size_t)(N + 1) * 4;
    int* deg     = (int*)p;   p += (size_t)N * 4;
    int* cnt     = (int*)p;   p += (size_t)N * 4;
    int* csr_src = (int*)p;   p += (size_t)E * 4;
    int* bsums   = (int*)p;   p += 1024 * 4;
    int* gs      = (int*)p;   p += NUM_GRAPHS * 4;
    int* ge      = (int*)p;   p += NUM_GRAPHS * 4;
    float* hg    = (float*)p; p += NUM_GRAPHS * D * 4;

    int nbN = (N + 255) / 256;
    int nbE = (E + 255) / 256;
    int nbW = (N * 64 + 255) / 256;  // wave-per-node grids

    hipMemsetAsync(deg, 0, (size_t)N * 4, stream);
    hipMemsetAsync(cnt, 0, (size_t)N * 4, stream);
    hipMemsetAsync(gs, 0x7f, NUM_GRAPHS * 4, stream);  // +huge
    hipMemsetAsync(ge, 0xff, NUM_GRAPHS * 4, stream);  // -1
    hipMemsetAsync(hg, 0, NUM_GRAPHS * D * 4, stream);

    // CSR build (shared by both layers)
    k_histo<<<nbE, 256, 0, stream>>>(dst, deg, E);
    k_scan_block<<<nbN, 256, 0, stream>>>(deg, row_ptr, bsums, N);
    k_scan_sums<<<1, 512, 0, stream>>>(bsums, nbN);
    k_scan_add<<<nbN, 256, 0, stream>>>(row_ptr, bsums, N, E);
    k_fill<<<nbE, 256, 0, stream>>>(src, dst, row_ptr, cnt, csr_src, E);

    dim3 ggrid((N + 63) / 64, 2);

    // Layer 1
    k_gemm128<<<ggrid, 256, 0, stream>>>(h, W1, featA, N);
    k_eler<<<nbW, 256, 0, stream>>>(featA, al1, ar1, el, er, N);
    k_aggregate<<<nbW, 256, 0, stream>>>(featA, el, er, row_ptr, csr_src, b1, featB, N);

    // Layer 2
    k_gemm128<<<ggrid, 256, 0, stream>>>(featB, W2, featA, N);
    k_eler<<<nbW, 256, 0, stream>>>(featA, al2, ar2, el, er, N);
    k_aggregate<<<nbW, 256, 0, stream>>>(featA, el, er, row_ptr, csr_src, b2, featB, N);

    // Pool + FC + log_softmax
    k_bounds_sorted<<<nbN, 256, 0, stream>>>(gid, gs, ge, N);
    k_pool_partial<<<dim3(NUM_GRAPHS, PCHUNK), 256, 0, stream>>>(featB, gs, ge, hg);
    k_final<<<1, 64, 0, stream>>>(hg, gs, ge, Wfc, bfc, out);
}

// Round 4
// 536.130 us; speedup vs baseline: 2.8852x; 1.3181x over previous
//
#include <hip/hip_runtime.h>
#include <math.h>

#define NUM_GRAPHS 64
#define D 128
#define PCHUNK 16

__device__ __forceinline__ unsigned bf16rne(float x) {
    unsigned u = __float_as_uint(x);
    return (u + 0x7fffu + ((u >> 16) & 1u)) >> 16;
}
__device__ __forceinline__ float bflo(unsigned u) { return __uint_as_float(u << 16); }
__device__ __forceinline__ float bfhi(unsigned u) { return __uint_as_float(u & 0xffff0000u); }

// ---------------- CSR build ----------------

__global__ void k_histo(const int* __restrict__ dst, int* __restrict__ deg, int E) {
    int e = blockIdx.x * blockDim.x + threadIdx.x;
    if (e < E) atomicAdd(&deg[dst[e]], 1);
}

__global__ void k_scan_block(const int* __restrict__ deg, int* __restrict__ row_ptr,
                             int* __restrict__ bsums, int N) {
    __shared__ int sm[256];
    int t = threadIdx.x;
    int i = blockIdx.x * 256 + t;
    int v = (i < N) ? deg[i] : 0;
    sm[t] = v;
    __syncthreads();
    for (int off = 1; off < 256; off <<= 1) {
        int y = (t >= off) ? sm[t - off] : 0;
        __syncthreads();
        sm[t] += y;
        __syncthreads();
    }
    if (i < N) row_ptr[i] = sm[t] - v;          // exclusive
    if (t == 255) bsums[blockIdx.x] = sm[255];  // block total
}

__global__ void k_scan_sums(int* __restrict__ bsums, int nb) {
    __shared__ int sm[512];
    int t = threadIdx.x;
    int v = (t < nb) ? bsums[t] : 0;
    sm[t] = v;
    __syncthreads();
    for (int off = 1; off < 512; off <<= 1) {
        int y = (t >= off) ? sm[t - off] : 0;
        __syncthreads();
        sm[t] += y;
        __syncthreads();
    }
    if (t < nb) bsums[t] = sm[t] - v;           // exclusive block offsets
}

__global__ void k_scan_add(int* __restrict__ row_ptr, const int* __restrict__ bsums,
                           int N, int E) {
    int i = blockIdx.x * 256 + threadIdx.x;
    if (i < N) row_ptr[i] += bsums[blockIdx.x];
    if (i == 0) row_ptr[N] = E;
}

// ---------------- fused GEMM(+el/er epilogue, bf16 out) + CSR-fill ----------------
// Role split across blocks (Bresenham stripe so gemm and fill co-schedule):
// gemm blocks compute 64 rows x all 128 cols of Y = X@W, reduce el/er per row
// in-register, store Y as bf16 (the gather table). Fill blocks do the CSR
// scatter (independent work, overlapped to hide the GEMM behind the
// write-amplified scatter).

__global__ __launch_bounds__(256) void k_gemm_eler_fill(
    const float* __restrict__ X, const float* __restrict__ W,
    const float* __restrict__ al, const float* __restrict__ ar,
    unsigned short* __restrict__ feat16, float* __restrict__ el,
    float* __restrict__ er, int N, int gemmBlocks,
    const int* __restrict__ src, const int* __restrict__ dstp,
    const int* __restrict__ row_ptr, int* __restrict__ cnt,
    int* __restrict__ csr_src, int E) {
    int bx = blockIdx.x;
    int T = gridDim.x;
    int g0 = (int)((long long)bx * gemmBlocks / T);
    int g1 = (int)((long long)(bx + 1) * gemmBlocks / T);

    if (g1 == g0) {
        // ---- fill role ----
        int fid = bx - g0;                       // # fill blocks before bx
        int e = fid * 256 + threadIdx.x;
        if (e < E) {
            int d = dstp[e];
            int p = row_ptr[d] + atomicAdd(&cnt[d], 1);
            csr_src[p] = src[e];
        }
        return;
    }

    // ---- gemm role ----
    __shared__ float As[64][20];   // pad 20: keeps 16B alignment, breaks bank stride
    __shared__ float Bs[16][128];
    int tid = threadIdx.x;
    int tx = tid & 15, ty = tid >> 4;            // tx: 8-col group, ty: 4-row group
    int row0 = g0 * 64;
    if (row0 >= N) return;
    float acc[4][8] = {};
    int lr = tid >> 2, lc = (tid & 3) * 4;       // As staging
    int br = tid >> 4, bc = (tid & 15) * 8;      // Bs staging
    for (int k0 = 0; k0 < 128; k0 += 16) {
        int gr = row0 + lr;
        float4 av = (gr < N) ? *(const float4*)&X[(size_t)gr * D + k0 + lc]
                             : make_float4(0.f, 0.f, 0.f, 0.f);
        *(float4*)&As[lr][lc] = av;
        *(float4*)&Bs[br][bc] = *(const float4*)&W[(size_t)(k0 + br) * D + bc];
        *(float4*)&Bs[br][bc + 4] = *(const float4*)&W[(size_t)(k0 + br) * D + bc + 4];
        __syncthreads();
        #pragma unroll
        for (int kk = 0; kk < 16; ++kk) {
            float a[4];
            #pragma unroll
            for (int i = 0; i < 4; ++i) a[i] = As[ty * 4 + i][kk];
            float4 b0 = *(float4*)&Bs[kk][tx * 8];
            float4 b1 = *(float4*)&Bs[kk][tx * 8 + 4];
            float bb[8] = {b0.x, b0.y, b0.z, b0.w, b1.x, b1.y, b1.z, b1.w};
            #pragma unroll
            for (int i = 0; i < 4; ++i)
                #pragma unroll
                for (int j = 0; j < 8; ++j) acc[i][j] += a[i] * bb[j];
        }
        __syncthreads();
    }
    float4 a0 = *(const float4*)&al[tx * 8], a1 = *(const float4*)&al[tx * 8 + 4];
    float4 r0 = *(const float4*)&ar[tx * 8], r1 = *(const float4*)&ar[tx * 8 + 4];
    float alv[8] = {a0.x, a0.y, a0.z, a0.w, a1.x, a1.y, a1.z, a1.w};
    float arv[8] = {r0.x, r0.y, r0.z, r0.w, r1.x, r1.y, r1.z, r1.w};
    #pragma unroll
    for (int i = 0; i < 4; ++i) {
        int row = row0 + ty * 4 + i;
        if (row >= N) continue;   // uniform across each 16-lane shfl group
        float pl = 0.f, pr = 0.f;
        #pragma unroll
        for (int j = 0; j < 8; ++j) { pl += acc[i][j] * alv[j]; pr += acc[i][j] * arv[j]; }
        #pragma unroll
        for (int o = 1; o < 16; o <<= 1) {
            pl += __shfl_xor(pl, o);
            pr += __shfl_xor(pr, o);
        }
        if (tx == 0) { el[row] = pl; er[row] = pr; }
        uint4 pk;
        pk.x = bf16rne(acc[i][0]) | (bf16rne(acc[i][1]) << 16);
        pk.y = bf16rne(acc[i][2]) | (bf16rne(acc[i][3]) << 16);
        pk.z = bf16rne(acc[i][4]) | (bf16rne(acc[i][5]) << 16);
        pk.w = bf16rne(acc[i][6]) | (bf16rne(acc[i][7]) << 16);
        ((uint4*)(feat16 + (size_t)row * D))[tx] = pk;
    }
}

// ---------------- fused edge-softmax + aggregation + bias + relu ----------------
// One wave per dst. Quarter-waves (16 lanes = all 128 bf16 ch) take edges
// stride 4, unrolled x2 -> 8 gather rows in flight, half the bytes vs fp32.

__global__ __launch_bounds__(256) void k_aggregate(
    const unsigned short* __restrict__ feat16, const float* __restrict__ el,
    const float* __restrict__ er, const int* __restrict__ row_ptr,
    const int* __restrict__ csr_src, const float* __restrict__ bias,
    float* __restrict__ out, int N) {
    int wid = (blockIdx.x * blockDim.x + threadIdx.x) >> 6;
    int lane = threadIdx.x & 63;
    if (wid >= N) return;
    int beg = row_ptr[wid], end = row_ptr[wid + 1];
    int deg = end - beg;
    float erd = er[wid];

    float m = -INFINITY;
    for (int j = lane; j < deg; j += 64) {
        float e = el[csr_src[beg + j]] + erd;
        e = e >= 0.f ? e : 0.2f * e;
        m = fmaxf(m, e);
    }
    #pragma unroll
    for (int o = 32; o >= 1; o >>= 1) m = fmaxf(m, __shfl_xor(m, o));

    float s = 0.f;
    for (int j = lane; j < deg; j += 64) {
        float e = el[csr_src[beg + j]] + erd;
        e = e >= 0.f ? e : 0.2f * e;
        s += __expf(e - m);
    }
    #pragma unroll
    for (int o = 32; o >= 1; o >>= 1) s += __shfl_xor(s, o);
    float inv = (deg > 0) ? 1.f / s : 0.f;

    int qa = lane >> 4, sub = lane & 15;
    const uint4* f16 = (const uint4*)feat16;
    float acc[8] = {};
    int j = beg + qa;
    for (; j + 4 < end; j += 8) {
        int sn0 = csr_src[j], sn1 = csr_src[j + 4];
        float e0 = el[sn0] + erd; e0 = e0 >= 0.f ? e0 : 0.2f * e0;
        float e1 = el[sn1] + erd; e1 = e1 >= 0.f ? e1 : 0.2f * e1;
        float w0 = __expf(e0 - m) * inv;
        float w1 = __expf(e1 - m) * inv;
        uint4 q0 = f16[(size_t)sn0 * 16 + sub];
        uint4 q1 = f16[(size_t)sn1 * 16 + sub];
        acc[0] += w0 * bflo(q0.x) + w1 * bflo(q1.x);
        acc[1] += w0 * bfhi(q0.x) + w1 * bfhi(q1.x);
        acc[2] += w0 * bflo(q0.y) + w1 * bflo(q1.y);
        acc[3] += w0 * bfhi(q0.y) + w1 * bfhi(q1.y);
        acc[4] += w0 * bflo(q0.z) + w1 * bflo(q1.z);
        acc[5] += w0 * bfhi(q0.z) + w1 * bfhi(q1.z);
        acc[6] += w0 * bflo(q0.w) + w1 * bflo(q1.w);
        acc[7] += w0 * bfhi(q0.w) + w1 * bfhi(q1.w);
    }
    if (j < end) {
        int sn = csr_src[j];
        float e = el[sn] + erd; e = e >= 0.f ? e : 0.2f * e;
        float w = __expf(e - m) * inv;
        uint4 q = f16[(size_t)sn * 16 + sub];
        acc[0] += w * bflo(q.x); acc[1] += w * bfhi(q.x);
        acc[2] += w * bflo(q.y); acc[3] += w * bfhi(q.y);
        acc[4] += w * bflo(q.z); acc[5] += w * bfhi(q.z);
        acc[6] += w * bflo(q.w); acc[7] += w * bfhi(q.w);
    }
    #pragma unroll
    for (int c = 0; c < 8; ++c) {
        acc[c] += __shfl_xor(acc[c], 16);
        acc[c] += __shfl_xor(acc[c], 32);
    }
    if (lane < 16) {
        float4 b0 = ((const float4*)bias)[lane * 2];
        float4 b1 = ((const float4*)bias)[lane * 2 + 1];
        float4 o0, o1;
        o0.x = fmaxf(acc[0] + b0.x, 0.f);
        o0.y = fmaxf(acc[1] + b0.y, 0.f);
        o0.z = fmaxf(acc[2] + b0.z, 0.f);
        o0.w = fmaxf(acc[3] + b0.w, 0.f);
        o1.x = fmaxf(acc[4] + b1.x, 0.f);
        o1.y = fmaxf(acc[5] + b1.y, 0.f);
        o1.z = fmaxf(acc[6] + b1.z, 0.f);
        o1.w = fmaxf(acc[7] + b1.w, 0.f);
        ((float4*)(out + (size_t)wid * D))[lane * 2] = o0;
        ((float4*)(out + (size_t)wid * D))[lane * 2 + 1] = o1;
    }
}

// ---------------- pooling ----------------

__global__ void k_bounds_sorted(const int* __restrict__ gid, int* __restrict__ gs,
                                int* __restrict__ ge, int N) {
    int n = blockIdx.x * blockDim.x + threadIdx.x;
    if (n >= N) return;
    int g = gid[n];
    if (n == 0 || gid[n - 1] != g) gs[g] = n;
    if (n == N - 1 || gid[n + 1] != g) ge[g] = n;
}

__global__ __launch_bounds__(256) void k_pool_partial(const float* __restrict__ x,
                                                      const int* __restrict__ gs,
                                                      const int* __restrict__ ge,
                                                      float* __restrict__ hg) {
    int g = blockIdx.x, c = blockIdx.y;
    int start = gs[g], last = ge[g];
    if (start > last) return;
    int sub = threadIdx.x & 31;
    int r   = threadIdx.x >> 5;
    const float4* x4 = (const float4*)x;
    float4 acc = make_float4(0.f, 0.f, 0.f, 0.f);
    for (int n = start + c * 8 + r; n <= last; n += PCHUNK * 8) {
        float4 v = x4[(size_t)n * 32 + sub];
        acc.x += v.x; acc.y += v.y; acc.z += v.z; acc.w += v.w;
    }
    __shared__ float4 sm[256];
    sm[threadIdx.x] = acc;
    __syncthreads();
    for (int off = 4; off >= 1; off >>= 1) {
        if (r < off) {
            float4 o = sm[threadIdx.x + off * 32];
            float4 v = sm[threadIdx.x];
            v.x += o.x; v.y += o.y; v.z += o.z; v.w += o.w;
            sm[threadIdx.x] = v;
        }
        __syncthreads();
    }
    if (r == 0) {
        float4 v = sm[sub];
        atomicAdd(&hg[g * D + sub * 4 + 0], v.x);
        atomicAdd(&hg[g * D + sub * 4 + 1], v.y);
        atomicAdd(&hg[g * D + sub * 4 + 2], v.z);
        atomicAdd(&hg[g * D + sub * 4 + 3], v.w);
    }
}

__global__ void k_final(const float* __restrict__ hg, const int* __restrict__ gs,
                        const int* __restrict__ ge, const float* __restrict__ Wfc,
                        const float* __restrict__ bfc, float* __restrict__ out) {
    int g = threadIdx.x;
    if (g >= NUM_GRAPHS) return;
    int start = gs[g], last = ge[g];
    float cnt = (start <= last) ? (float)(last - start + 1) : 1.f;
    float ic = 1.f / cnt;
    float l0 = bfc[0], l1 = bfc[1];
    for (int d = 0; d < D; d++) {
        float v = hg[g * D + d] * ic;
        l0 += v * Wfc[2 * d];
        l1 += v * Wfc[2 * d + 1];
    }
    float mm = fmaxf(l0, l1);
    float lse = mm + logf(expf(l0 - mm) + expf(l1 - mm));
    out[2 * g] = l0 - lse;
    out[2 * g + 1] = l1 - lse;
}

// ---------------- launch ----------------

extern "C" void kernel_launch(void* const* d_in, const int* in_sizes, int n_in,
                              void* d_out, int out_size, void* d_ws, size_t ws_size,
                              hipStream_t stream) {
    const float* h   = (const float*)d_in[0];
    const int* src   = (const int*)d_in[1];
    const int* dst   = (const int*)d_in[2];
    const int* gid   = (const int*)d_in[3];
    const float* W1  = (const float*)d_in[4];
    const float* al1 = (const float*)d_in[5];
    const float* ar1 = (const float*)d_in[6];
    const float* b1  = (const float*)d_in[7];
    const float* W2  = (const float*)d_in[8];
    const float* al2 = (const float*)d_in[9];
    const float* ar2 = (const float*)d_in[10];
    const float* b2  = (const float*)d_in[11];
    const float* Wfc = (const float*)d_in[12];
    const float* bfc = (const float*)d_in[13];
    float* out = (float*)d_out;

    int N = in_sizes[0] / D;
    int E = in_sizes[1];

    char* p = (char*)d_ws;
    unsigned short* feat16 = (unsigned short*)p; p += (size_t)N * D * 2;
    float* featB = (float*)p; p += (size_t)N * D * 4;
    float* el    = (float*)p; p += (size_t)N * 4;
    float* er    = (float*)p; p += (size_t)N * 4;
    int* row_ptr = (int*)p;   p += (size_t)(N + 4) * 4;
    int* deg     = (int*)p;   p += (size_t)N * 4;   // deg+cnt adjacent: one memset
    int* cnt     = (int*)p;   p += (size_t)N * 4;
    int* csr_src = (int*)p;   p += (size_t)E * 4;
    int* bsums   = (int*)p;   p += 1024 * 4;
    int* gs      = (int*)p;   p += NUM_GRAPHS * 4;
    int* ge      = (int*)p;   p += NUM_GRAPHS * 4;
    float* hg    = (float*)p; p += NUM_GRAPHS * D * 4;

    int nbN = (N + 255) / 256;
    int nbE = (E + 255) / 256;
    int nbW = (N * 64 + 255) / 256;  // wave-per-node grids
    int gemmBlocks = (N + 63) / 64;

    hipMemsetAsync(deg, 0, (size_t)N * 8, stream);           // deg + cnt
    hipMemsetAsync(gs, 0x7f, NUM_GRAPHS * 4, stream);        // +huge
    hipMemsetAsync(ge, 0xff, NUM_GRAPHS * 4, stream);        // -1
    hipMemsetAsync(hg, 0, NUM_GRAPHS * D * 4, stream);

    // CSR prefix (histogram + scan); fill is fused with layer-1 GEMM below
    k_histo<<<nbE, 256, 0, stream>>>(dst, deg, E);
    k_scan_block<<<nbN, 256, 0, stream>>>(deg, row_ptr, bsums, N);
    k_scan_sums<<<1, 512, 0, stream>>>(bsums, nbN);
    k_scan_add<<<nbN, 256, 0, stream>>>(row_ptr, bsums, N, E);

    // Layer 1: GEMM(+el/er, bf16 feat) overlapped with CSR fill
    k_gemm_eler_fill<<<gemmBlocks + nbE, 256, 0, stream>>>(
        h, W1, al1, ar1, feat16, el, er, N, gemmBlocks,
        src, dst, row_ptr, cnt, csr_src, E);
    k_aggregate<<<nbW, 256, 0, stream>>>(feat16, el, er, row_ptr, csr_src, b1, featB, N);

    // Layer 2: GEMM alone (grid == gemmBlocks -> every block takes gemm role)
    k_gemm_eler_fill<<<gemmBlocks, 256, 0, stream>>>(
        featB, W2, al2, ar2, feat16, el, er, N, gemmBlocks,
        src, dst, row_ptr, cnt, csr_src, 0);
    k_aggregate<<<nbW, 256, 0, stream>>>(feat16, el, er, row_ptr, csr_src, b2, featB, N);

    // Pool + FC + log_softmax
    k_bounds_sorted<<<nbN, 256, 0, stream>>>(gid, gs, ge, N);
    k_pool_partial<<<dim3(NUM_GRAPHS, PCHUNK), 256, 0, stream>>>(featB, gs, ge, hg);
    k_final<<<1, 64, 0, stream>>>(hg, gs, ge, Wfc, bfc, out);
}

// Round 5
// 476.719 us; speedup vs baseline: 3.2447x; 1.1246x over previous
//
#include <hip/hip_runtime.h>
#include <math.h>

#define NUM_GRAPHS 64
#define D 128
#define PCHUNK 16
#define MT 64   // GEMM rows per block

typedef __attribute__((ext_vector_type(8))) short bf16x8;
typedef __attribute__((ext_vector_type(4))) float f32x4;

__device__ __forceinline__ unsigned bf16rne(float x) {
    unsigned u = __float_as_uint(x);
    return (u + 0x7fffu + ((u >> 16) & 1u)) >> 16;
}
__device__ __forceinline__ float bflo(unsigned u) { return __uint_as_float(u << 16); }
__device__ __forceinline__ float bfhi(unsigned u) { return __uint_as_float(u & 0xffff0000u); }

// ---------------- CSR build ----------------

__global__ void k_histo(const int* __restrict__ dst, int* __restrict__ deg, int E) {
    int e = blockIdx.x * blockDim.x + threadIdx.x;
    if (e < E) atomicAdd(&deg[dst[e]], 1);
}

__global__ void k_scan_block(const int* __restrict__ deg, int* __restrict__ row_ptr,
                             int* __restrict__ bsums, int N) {
    __shared__ int sm[256];
    int t = threadIdx.x;
    int i = blockIdx.x * 256 + t;
    int v = (i < N) ? deg[i] : 0;
    sm[t] = v;
    __syncthreads();
    for (int off = 1; off < 256; off <<= 1) {
        int y = (t >= off) ? sm[t - off] : 0;
        __syncthreads();
        sm[t] += y;
        __syncthreads();
    }
    if (i < N) row_ptr[i] = sm[t] - v;
    if (t == 255) bsums[blockIdx.x] = sm[255];
}

__global__ void k_scan_sums(int* __restrict__ bsums, int nb) {
    __shared__ int sm[512];
    int t = threadIdx.x;
    int v = (t < nb) ? bsums[t] : 0;
    sm[t] = v;
    __syncthreads();
    for (int off = 1; off < 512; off <<= 1) {
        int y = (t >= off) ? sm[t - off] : 0;
        __syncthreads();
        sm[t] += y;
        __syncthreads();
    }
    if (t < nb) bsums[t] = sm[t] - v;
}

__global__ void k_scan_add(int* __restrict__ row_ptr, const int* __restrict__ bsums,
                           int N, int E) {
    int i = blockIdx.x * 256 + threadIdx.x;
    if (i < N) row_ptr[i] += bsums[blockIdx.x];
    if (i == 0) row_ptr[N] = E;
}

// ---------------- W -> transposed bf16 (Wt[n][k]) ----------------

__global__ void k_prep_w(const float* __restrict__ W1, const float* __restrict__ W2,
                         unsigned short* __restrict__ Wt1, unsigned short* __restrict__ Wt2) {
    const float* W = blockIdx.y ? W2 : W1;
    unsigned short* Wt = blockIdx.y ? Wt2 : Wt1;
    int n = blockIdx.x * 16 + (threadIdx.x >> 4);
    int c = threadIdx.x & 15;
    unsigned v[8];
    #pragma unroll
    for (int j = 0; j < 8; ++j) v[j] = bf16rne(W[(c * 8 + j) * D + n]);
    uint4 pk;
    pk.x = v[0] | (v[1] << 16);
    pk.y = v[2] | (v[3] << 16);
    pk.z = v[4] | (v[5] << 16);
    pk.w = v[6] | (v[7] << 16);
    ((uint4*)Wt)[n * 16 + c] = pk;
}

// ---------------- MFMA GEMM (+el/er, bf16 out) fused with CSR fill ----------------
// Y[N,128] = X @ W via v_mfma_f32_16x16x32_bf16. Block = 64 rows, 4 waves of
// 16 rows x 128 cols. LDS chunks (16B = 8 bf16) XOR-swizzled: chunk c of row
// n lives at slot c ^ (n&15) -> <=2-way bank conflicts on all reads/writes.
// Fill role (Bresenham stripe) overlaps the scatter as in R3/R4.

__global__ __launch_bounds__(256) void k_gemm_mfma_fill(
    const void* __restrict__ Xv, int x_fp32,
    const unsigned short* __restrict__ Wt16,
    const float* __restrict__ al, const float* __restrict__ ar,
    unsigned short* __restrict__ feat16, float* __restrict__ el,
    float* __restrict__ er, int N, int gemmBlocks,
    const int* __restrict__ src, const int* __restrict__ dstp,
    const int* __restrict__ row_ptr, int* __restrict__ cnt,
    int* __restrict__ csr_src, int E) {
    int bx = blockIdx.x;
    int T = gridDim.x;
    int g0 = (int)((long long)bx * gemmBlocks / T);
    int g1 = (int)((long long)(bx + 1) * gemmBlocks / T);

    if (g1 == g0) {
        int fid = bx - g0;
        int e = fid * 256 + threadIdx.x;
        if (e < E) {
            int d = dstp[e];
            int p = row_ptr[d] + atomicAdd(&cnt[d], 1);
            csr_src[p] = src[e];
        }
        return;
    }

    __shared__ uint4 WsU[128 * 16];  // 32 KB
    __shared__ uint4 XsU[MT * 16];   // 16 KB
    int tid = threadIdx.x;
    int row0 = g0 * MT;

    // stage W (already transposed bf16: Wt[n][k])
    for (int idx = tid; idx < 128 * 16; idx += 256) {
        int n = idx >> 4, c = idx & 15;
        WsU[(n << 4) | (c ^ (n & 15))] = ((const uint4*)Wt16)[idx];
    }
    // stage X (fp32 -> bf16 convert, or bf16 passthrough)
    if (x_fp32) {
        const float4* X4 = (const float4*)Xv;
        for (int idx = tid; idx < MT * 16; idx += 256) {
            int n = idx >> 4, c = idx & 15;
            int row = row0 + n;
            uint4 o = make_uint4(0, 0, 0, 0);
            if (row < N) {
                float4 f0 = X4[(size_t)row * 32 + c * 2];
                float4 f1 = X4[(size_t)row * 32 + c * 2 + 1];
                o.x = bf16rne(f0.x) | (bf16rne(f0.y) << 16);
                o.y = bf16rne(f0.z) | (bf16rne(f0.w) << 16);
                o.z = bf16rne(f1.x) | (bf16rne(f1.y) << 16);
                o.w = bf16rne(f1.z) | (bf16rne(f1.w) << 16);
            }
            XsU[(n << 4) | (c ^ (n & 15))] = o;
        }
    } else {
        const uint4* X16 = (const uint4*)Xv;
        for (int idx = tid; idx < MT * 16; idx += 256) {
            int n = idx >> 4, c = idx & 15;
            int row = row0 + n;
            uint4 o = make_uint4(0, 0, 0, 0);
            if (row < N) o = X16[(size_t)row * 16 + c];
            XsU[(n << 4) | (c ^ (n & 15))] = o;
        }
    }
    __syncthreads();

    int lane = tid & 63, w = tid >> 6;
    int quad = lane >> 4, l16 = lane & 15;
    const bf16x8* WsF = (const bf16x8*)WsU;
    const bf16x8* XsF = (const bf16x8*)XsU;
    f32x4 acc[8];
    #pragma unroll
    for (int i = 0; i < 8; ++i) acc[i] = (f32x4){0.f, 0.f, 0.f, 0.f};

    int arow = w * 16 + l16;    // arow & 15 == l16
    #pragma unroll
    for (int ks = 0; ks < 4; ++ks) {
        int c = ks * 4 + quad;
        bf16x8 A = XsF[(arow << 4) | (c ^ l16)];
        #pragma unroll
        for (int nt = 0; nt < 8; ++nt) {
            bf16x8 B = WsF[((nt * 16 + l16) << 4) | (c ^ l16)];
            acc[nt] = __builtin_amdgcn_mfma_f32_16x16x32_bf16(A, B, acc[nt], 0, 0, 0);
        }
    }

    // el/er epilogue from fp32 accumulators
    float alv[8], arv[8];
    #pragma unroll
    for (int nt = 0; nt < 8; ++nt) { alv[nt] = al[nt * 16 + l16]; arv[nt] = ar[nt * 16 + l16]; }
    #pragma unroll
    for (int r = 0; r < 4; ++r) {
        float pl = 0.f, pr = 0.f;
        #pragma unroll
        for (int nt = 0; nt < 8; ++nt) { pl += acc[nt][r] * alv[nt]; pr += acc[nt][r] * arv[nt]; }
        #pragma unroll
        for (int o = 1; o < 16; o <<= 1) { pl += __shfl_xor(pl, o); pr += __shfl_xor(pr, o); }
        int row = row0 + w * 16 + quad * 4 + r;
        if (l16 == 0 && row < N) { el[row] = pl; er[row] = pr; }
    }

    // C -> LDS bf16 (own-wave rows of Xs; per-wave private, no barrier needed
    // before, compiler orders intra-wave LDS)
    unsigned short* XsS = (unsigned short*)XsU;
    #pragma unroll
    for (int nt = 0; nt < 8; ++nt)
        #pragma unroll
        for (int r = 0; r < 4; ++r) {
            int lrow = w * 16 + quad * 4 + r;
            int col = nt * 16 + l16;
            int ch = col >> 3;
            int sc = ch ^ (lrow & 15);
            XsS[lrow * 128 + sc * 8 + (col & 7)] = (unsigned short)bf16rne(acc[nt][r]);
        }
    __syncthreads();
    for (int idx = tid; idx < MT * 16; idx += 256) {
        int n = idx >> 4, c = idx & 15;
        int row = row0 + n;
        if (row < N) ((uint4*)feat16)[(size_t)row * 16 + c] = XsU[(n << 4) | (c ^ (n & 15))];
    }
}

// ---------------- fused edge-softmax + aggregation + bias + relu ----------------

template <bool OUT_BF16>
__global__ __launch_bounds__(256) void k_aggregate(
    const unsigned short* __restrict__ feat16, const float* __restrict__ el,
    const float* __restrict__ er, const int* __restrict__ row_ptr,
    const int* __restrict__ csr_src, const float* __restrict__ bias,
    void* __restrict__ outv, int N) {
    int wid = (blockIdx.x * blockDim.x + threadIdx.x) >> 6;
    int lane = threadIdx.x & 63;
    if (wid >= N) return;
    int beg = row_ptr[wid], end = row_ptr[wid + 1];
    int deg = end - beg;
    float erd = er[wid];

    float m = -INFINITY;
    for (int j = lane; j < deg; j += 64) {
        float e = el[csr_src[beg + j]] + erd;
        e = e >= 0.f ? e : 0.2f * e;
        m = fmaxf(m, e);
    }
    #pragma unroll
    for (int o = 32; o >= 1; o >>= 1) m = fmaxf(m, __shfl_xor(m, o));

    float s = 0.f;
    for (int j = lane; j < deg; j += 64) {
        float e = el[csr_src[beg + j]] + erd;
        e = e >= 0.f ? e : 0.2f * e;
        s += __expf(e - m);
    }
    #pragma unroll
    for (int o = 32; o >= 1; o >>= 1) s += __shfl_xor(s, o);
    float inv = (deg > 0) ? 1.f / s : 0.f;

    int qa = lane >> 4, sub = lane & 15;
    const uint4* f16 = (const uint4*)feat16;
    float acc[8] = {};
    int j = beg + qa;
    for (; j + 4 < end; j += 8) {
        int sn0 = csr_src[j], sn1 = csr_src[j + 4];
        float e0 = el[sn0] + erd; e0 = e0 >= 0.f ? e0 : 0.2f * e0;
        float e1 = el[sn1] + erd; e1 = e1 >= 0.f ? e1 : 0.2f * e1;
        float w0 = __expf(e0 - m) * inv;
        float w1 = __expf(e1 - m) * inv;
        uint4 q0 = f16[(size_t)sn0 * 16 + sub];
        uint4 q1 = f16[(size_t)sn1 * 16 + sub];
        acc[0] += w0 * bflo(q0.x) + w1 * bflo(q1.x);
        acc[1] += w0 * bfhi(q0.x) + w1 * bfhi(q1.x);
        acc[2] += w0 * bflo(q0.y) + w1 * bflo(q1.y);
        acc[3] += w0 * bfhi(q0.y) + w1 * bfhi(q1.y);
        acc[4] += w0 * bflo(q0.z) + w1 * bflo(q1.z);
        acc[5] += w0 * bfhi(q0.z) + w1 * bfhi(q1.z);
        acc[6] += w0 * bflo(q0.w) + w1 * bflo(q1.w);
        acc[7] += w0 * bfhi(q0.w) + w1 * bfhi(q1.w);
    }
    if (j < end) {
        int sn = csr_src[j];
        float e = el[sn] + erd; e = e >= 0.f ? e : 0.2f * e;
        float w = __expf(e - m) * inv;
        uint4 q = f16[(size_t)sn * 16 + sub];
        acc[0] += w * bflo(q.x); acc[1] += w * bfhi(q.x);
        acc[2] += w * bflo(q.y); acc[3] += w * bfhi(q.y);
        acc[4] += w * bflo(q.z); acc[5] += w * bfhi(q.z);
        acc[6] += w * bflo(q.w); acc[7] += w * bfhi(q.w);
    }
    #pragma unroll
    for (int c = 0; c < 8; ++c) {
        acc[c] += __shfl_xor(acc[c], 16);
        acc[c] += __shfl_xor(acc[c], 32);
    }
    if (lane < 16) {
        float4 b0 = ((const float4*)bias)[lane * 2];
        float4 b1 = ((const float4*)bias)[lane * 2 + 1];
        float v[8];
        v[0] = fmaxf(acc[0] + b0.x, 0.f);
        v[1] = fmaxf(acc[1] + b0.y, 0.f);
        v[2] = fmaxf(acc[2] + b0.z, 0.f);
        v[3] = fmaxf(acc[3] + b0.w, 0.f);
        v[4] = fmaxf(acc[4] + b1.x, 0.f);
        v[5] = fmaxf(acc[5] + b1.y, 0.f);
        v[6] = fmaxf(acc[6] + b1.z, 0.f);
        v[7] = fmaxf(acc[7] + b1.w, 0.f);
        if (OUT_BF16) {
            uint4 pk;
            pk.x = bf16rne(v[0]) | (bf16rne(v[1]) << 16);
            pk.y = bf16rne(v[2]) | (bf16rne(v[3]) << 16);
            pk.z = bf16rne(v[4]) | (bf16rne(v[5]) << 16);
            pk.w = bf16rne(v[6]) | (bf16rne(v[7]) << 16);
            ((uint4*)outv)[(size_t)wid * 16 + lane] = pk;
        } else {
            float4 o0 = make_float4(v[0], v[1], v[2], v[3]);
            float4 o1 = make_float4(v[4], v[5], v[6], v[7]);
            ((float4*)outv)[(size_t)wid * 32 + lane * 2] = o0;
            ((float4*)outv)[(size_t)wid * 32 + lane * 2 + 1] = o1;
        }
    }
}

// ---------------- pooling ----------------

__global__ void k_bounds_sorted(const int* __restrict__ gid, int* __restrict__ gs,
                                int* __restrict__ ge, int N) {
    int n = blockIdx.x * blockDim.x + threadIdx.x;
    if (n >= N) return;
    int g = gid[n];
    if (n == 0 || gid[n - 1] != g) gs[g] = n;
    if (n == N - 1 || gid[n + 1] != g) ge[g] = n;
}

__global__ __launch_bounds__(256) void k_pool_partial(const float* __restrict__ x,
                                                      const int* __restrict__ gs,
                                                      const int* __restrict__ ge,
                                                      float* __restrict__ hg) {
    int g = blockIdx.x, c = blockIdx.y;
    int start = gs[g], last = ge[g];
    if (start > last) return;
    int sub = threadIdx.x & 31;
    int r   = threadIdx.x >> 5;
    const float4* x4 = (const float4*)x;
    float4 acc = make_float4(0.f, 0.f, 0.f, 0.f);
    for (int n = start + c * 8 + r; n <= last; n += PCHUNK * 8) {
        float4 v = x4[(size_t)n * 32 + sub];
        acc.x += v.x; acc.y += v.y; acc.z += v.z; acc.w += v.w;
    }
    __shared__ float4 sm[256];
    sm[threadIdx.x] = acc;
    __syncthreads();
    for (int off = 4; off >= 1; off >>= 1) {
        if (r < off) {
            float4 o = sm[threadIdx.x + off * 32];
            float4 v = sm[threadIdx.x];
            v.x += o.x; v.y += o.y; v.z += o.z; v.w += o.w;
            sm[threadIdx.x] = v;
        }
        __syncthreads();
    }
    if (r == 0) {
        float4 v = sm[sub];
        atomicAdd(&hg[g * D + sub * 4 + 0], v.x);
        atomicAdd(&hg[g * D + sub * 4 + 1], v.y);
        atomicAdd(&hg[g * D + sub * 4 + 2], v.z);
        atomicAdd(&hg[g * D + sub * 4 + 3], v.w);
    }
}

__global__ void k_final(const float* __restrict__ hg, const int* __restrict__ gs,
                        const int* __restrict__ ge, const float* __restrict__ Wfc,
                        const float* __restrict__ bfc, float* __restrict__ out) {
    int g = threadIdx.x;
    if (g >= NUM_GRAPHS) return;
    int start = gs[g], last = ge[g];
    float cnt = (start <= last) ? (float)(last - start + 1) : 1.f;
    float ic = 1.f / cnt;
    float l0 = bfc[0], l1 = bfc[1];
    for (int d = 0; d < D; d++) {
        float v = hg[g * D + d] * ic;
        l0 += v * Wfc[2 * d];
        l1 += v * Wfc[2 * d + 1];
    }
    float mm = fmaxf(l0, l1);
    float lse = mm + logf(expf(l0 - mm) + expf(l1 - mm));
    out[2 * g] = l0 - lse;
    out[2 * g + 1] = l1 - lse;
}

// ---------------- launch ----------------

extern "C" void kernel_launch(void* const* d_in, const int* in_sizes, int n_in,
                              void* d_out, int out_size, void* d_ws, size_t ws_size,
                              hipStream_t stream) {
    const float* h   = (const float*)d_in[0];
    const int* src   = (const int*)d_in[1];
    const int* dst   = (const int*)d_in[2];
    const int* gid   = (const int*)d_in[3];
    const float* W1  = (const float*)d_in[4];
    const float* al1 = (const float*)d_in[5];
    const float* ar1 = (const float*)d_in[6];
    const float* b1  = (const float*)d_in[7];
    const float* W2  = (const float*)d_in[8];
    const float* al2 = (const float*)d_in[9];
    const float* ar2 = (const float*)d_in[10];
    const float* b2  = (const float*)d_in[11];
    const float* Wfc = (const float*)d_in[12];
    const float* bfc = (const float*)d_in[13];
    float* out = (float*)d_out;

    int N = in_sizes[0] / D;
    int E = in_sizes[1];

    char* p = (char*)d_ws;
    unsigned short* feat16  = (unsigned short*)p; p += (size_t)N * D * 2;   // GEMM out
    unsigned short* featAgg = (unsigned short*)p; p += (size_t)N * D * 2;   // agg1 out (bf16)
    float* featB = (float*)p; p += (size_t)N * D * 4;                       // agg2 out (fp32)
    float* el    = (float*)p; p += (size_t)N * 4;
    float* er    = (float*)p; p += (size_t)N * 4;
    int* row_ptr = (int*)p;   p += (size_t)(N + 4) * 4;
    int* deg     = (int*)p;   p += (size_t)N * 4;
    int* cnt     = (int*)p;   p += (size_t)N * 4;
    int* csr_src = (int*)p;   p += (size_t)E * 4;
    int* bsums   = (int*)p;   p += 1024 * 4;
    int* gs      = (int*)p;   p += NUM_GRAPHS * 4;
    int* ge      = (int*)p;   p += NUM_GRAPHS * 4;
    float* hg    = (float*)p; p += NUM_GRAPHS * D * 4;
    unsigned short* Wt1 = (unsigned short*)p; p += D * D * 2;
    unsigned short* Wt2 = (unsigned short*)p; p += D * D * 2;

    int nbN = (N + 255) / 256;
    int nbE = (E + 255) / 256;
    int nbW = (N * 64 + 255) / 256;
    int gemmB = (N + MT - 1) / MT;

    hipMemsetAsync(deg, 0, (size_t)N * 8, stream);           // deg + cnt
    hipMemsetAsync(gs, 0x7f, NUM_GRAPHS * 4, stream);
    hipMemsetAsync(ge, 0xff, NUM_GRAPHS * 4, stream);
    hipMemsetAsync(hg, 0, NUM_GRAPHS * D * 4, stream);

    // CSR prefix + weight prep
    k_histo<<<nbE, 256, 0, stream>>>(dst, deg, E);
    k_prep_w<<<dim3(8, 2), 256, 0, stream>>>(W1, W2, Wt1, Wt2);
    k_scan_block<<<nbN, 256, 0, stream>>>(deg, row_ptr, bsums, N);
    k_scan_sums<<<1, 512, 0, stream>>>(bsums, nbN);
    k_scan_add<<<nbN, 256, 0, stream>>>(row_ptr, bsums, N, E);

    // Layer 1: MFMA GEMM (fp32 in) + el/er + bf16 out, overlapped with CSR fill
    k_gemm_mfma_fill<<<gemmB + nbE, 256, 0, stream>>>(
        h, 1, Wt1, al1, ar1, feat16, el, er, N, gemmB,
        src, dst, row_ptr, cnt, csr_src, E);
    k_aggregate<true><<<nbW, 256, 0, stream>>>(feat16, el, er, row_ptr, csr_src,
                                               b1, featAgg, N);

    // Layer 2: MFMA GEMM (bf16 in), all blocks gemm role
    k_gemm_mfma_fill<<<gemmB, 256, 0, stream>>>(
        featAgg, 0, Wt2, al2, ar2, feat16, el, er, N, gemmB,
        src, dst, row_ptr, cnt, csr_src, 0);
    k_aggregate<false><<<nbW, 256, 0, stream>>>(feat16, el, er, row_ptr, csr_src,
                                                b2, featB, N);

    // Pool + FC + log_softmax
    k_bounds_sorted<<<nbN, 256, 0, stream>>>(gid, gs, ge, N);
    k_pool_partial<<<dim3(NUM_GRAPHS, PCHUNK), 256, 0, stream>>>(featB, gs, ge, hg);
    k_final<<<1, 64, 0, stream>>>(hg, gs, ge, Wfc, bfc, out);
}

// Round 6
// 404.645 us; speedup vs baseline: 3.8227x; 1.1781x over previous
//
#include <hip/hip_runtime.h>
#include <math.h>

#define NUM_GRAPHS 64
#define D 128
#define PCHUNK 16
#define MT 64      // GEMM rows per block
#define ETILE 4096 // edges per partition block

typedef __attribute__((ext_vector_type(8))) short bf16x8;
typedef __attribute__((ext_vector_type(4))) float f32x4;

__device__ __forceinline__ unsigned bf16rne(float x) {
    unsigned u = __float_as_uint(x);
    return (u + 0x7fffu + ((u >> 16) & 1u)) >> 16;
}
__device__ __forceinline__ float bflo(unsigned u) { return __uint_as_float(u << 16); }
__device__ __forceinline__ float bfhi(unsigned u) { return __uint_as_float(u & 0xffff0000u); }

// ---------------- bucket CSR build (counting sort, LDS-local) ----------------
// Bucket = 128 consecutive dst nodes (NB = ceil(N/128) <= 1024 for N <= 131072).
// Edge packed as u32: src (17 bits) | dst_local << 17.

__global__ __launch_bounds__(256) void k_bucket_hist(const int* __restrict__ dst,
                                                     int* __restrict__ bhist, int E) {
    __shared__ int h[1024];
    int tid = threadIdx.x;
    for (int i = tid; i < 1024; i += 256) h[i] = 0;
    __syncthreads();
    int e0 = blockIdx.x * ETILE;
    int e1 = min(e0 + ETILE, E);
    for (int i = e0 + tid; i < e1; i += 256) atomicAdd(&h[dst[i] >> 7], 1);
    __syncthreads();
    for (int i = tid; i < 1024; i += 256)
        if (h[i]) atomicAdd(&bhist[i], h[i]);
}

__global__ __launch_bounds__(1024) void k_bucket_scan(const int* __restrict__ bhist,
                                                      int* __restrict__ bbase,
                                                      int* __restrict__ bcur,
                                                      int NB, int E,
                                                      int* __restrict__ row_ptr, int N) {
    __shared__ int sm[1024];
    int t = threadIdx.x;
    int v = (t < NB) ? bhist[t] : 0;
    sm[t] = v;
    __syncthreads();
    for (int off = 1; off < 1024; off <<= 1) {
        int y = (t >= off) ? sm[t - off] : 0;
        __syncthreads();
        sm[t] += y;
        __syncthreads();
    }
    if (t < NB) { bbase[t] = sm[t] - v; bcur[t] = sm[t] - v; }
    if (t == 0) { bbase[NB] = E; row_ptr[N] = E; }
}

__global__ __launch_bounds__(256) void k_partition(const int* __restrict__ src,
                                                   const int* __restrict__ dst,
                                                   int* __restrict__ bcur,
                                                   unsigned* __restrict__ part, int E) {
    __shared__ int h[1024];
    __shared__ int cur[1024];
    int tid = threadIdx.x;
    for (int i = tid; i < 1024; i += 256) h[i] = 0;
    __syncthreads();
    int e0 = blockIdx.x * ETILE;
    int e1 = min(e0 + ETILE, E);
    for (int i = e0 + tid; i < e1; i += 256) atomicAdd(&h[dst[i] >> 7], 1);
    __syncthreads();
    for (int i = tid; i < 1024; i += 256) {
        int c = h[i];
        cur[i] = c ? atomicAdd(&bcur[i], c) : 0;   // reserve contiguous chunk
    }
    __syncthreads();
    for (int i = e0 + tid; i < e1; i += 256) {
        int d = dst[i];
        int b = d >> 7;
        int pos = atomicAdd(&cur[b], 1);
        part[pos] = (unsigned)src[i] | ((unsigned)(d & 127) << 17);
    }
}

// ---------------- W -> transposed bf16 (Wt[n][k]) ----------------

__global__ void k_prep_w(const float* __restrict__ W1, const float* __restrict__ W2,
                         unsigned short* __restrict__ Wt1, unsigned short* __restrict__ Wt2) {
    const float* W = blockIdx.y ? W2 : W1;
    unsigned short* Wt = blockIdx.y ? Wt2 : Wt1;
    int n = blockIdx.x * 16 + (threadIdx.x >> 4);
    int c = threadIdx.x & 15;
    unsigned v[8];
    #pragma unroll
    for (int j = 0; j < 8; ++j) v[j] = bf16rne(W[(c * 8 + j) * D + n]);
    uint4 pk;
    pk.x = v[0] | (v[1] << 16);
    pk.y = v[2] | (v[3] << 16);
    pk.z = v[4] | (v[5] << 16);
    pk.w = v[6] | (v[7] << 16);
    ((uint4*)Wt)[n * 16 + c] = pk;
}

// ---------------- MFMA GEMM (+el/er, bf16 out) fused with bucket->CSR ----------------
// gemm role: 64 rows x 128 cols via v_mfma_f32_16x16x32_bf16, XOR-swizzled LDS.
// sort role (Bresenham-striped): one block per bucket builds per-node CSR in
// LDS (counts -> scan -> scatter) -- all global writes land in the bucket's
// private region (single XCD, no line ping-pong).

__global__ __launch_bounds__(256) void k_gemm_mfma_sort(
    const void* __restrict__ Xv, int x_fp32,
    const unsigned short* __restrict__ Wt16,
    const float* __restrict__ al, const float* __restrict__ ar,
    unsigned short* __restrict__ feat16, float* __restrict__ el,
    float* __restrict__ er, int N, int gemmBlocks,
    const unsigned* __restrict__ part, const int* __restrict__ bbase,
    int* __restrict__ row_ptr, int* __restrict__ csr_src) {
    __shared__ uint4 WsU[128 * 16];  // 32 KB
    __shared__ uint4 XsU[MT * 16];   // 16 KB
    int bx = blockIdx.x;
    int T = gridDim.x;
    int g0 = (int)((long long)bx * gemmBlocks / T);
    int g1 = (int)((long long)(bx + 1) * gemmBlocks / T);
    int tid = threadIdx.x;

    if (g1 == g0) {
        // ---- sort role: bucket -> CSR ----
        int b = bx - g0;                     // bucket id
        int base = bbase[b];
        int bcnt = bbase[b + 1] - base;
        int* ldeg = (int*)XsU;
        int* lcur = ldeg + 128;
        if (tid < 128) ldeg[tid] = 0;
        __syncthreads();
        for (int i = tid; i < bcnt; i += 256)
            atomicAdd(&ldeg[part[base + i] >> 17], 1);
        __syncthreads();
        int myv = (tid < 128) ? ldeg[tid] : 0;
        for (int off = 1; off < 128; off <<= 1) {
            int y = 0;
            if (tid < 128 && tid >= off) y = ldeg[tid - off];
            __syncthreads();
            if (tid < 128) ldeg[tid] += y;
            __syncthreads();
        }
        if (tid < 128) {
            int excl = ldeg[tid] - myv;
            int node = (b << 7) + tid;
            if (node < N) row_ptr[node] = base + excl;
            lcur[tid] = base + excl;
        }
        __syncthreads();
        for (int i = tid; i < bcnt; i += 256) {
            unsigned v = part[base + i];
            int pos = atomicAdd(&lcur[v >> 17], 1);
            csr_src[pos] = (int)(v & 0x1FFFFu);
        }
        return;
    }

    // ---- gemm role ----
    int row0 = g0 * MT;

    for (int idx = tid; idx < 128 * 16; idx += 256) {
        int n = idx >> 4, c = idx & 15;
        WsU[(n << 4) | (c ^ (n & 15))] = ((const uint4*)Wt16)[idx];
    }
    if (x_fp32) {
        const float4* X4 = (const float4*)Xv;
        for (int idx = tid; idx < MT * 16; idx += 256) {
            int n = idx >> 4, c = idx & 15;
            int row = row0 + n;
            uint4 o = make_uint4(0, 0, 0, 0);
            if (row < N) {
                float4 f0 = X4[(size_t)row * 32 + c * 2];
                float4 f1 = X4[(size_t)row * 32 + c * 2 + 1];
                o.x = bf16rne(f0.x) | (bf16rne(f0.y) << 16);
                o.y = bf16rne(f0.z) | (bf16rne(f0.w) << 16);
                o.z = bf16rne(f1.x) | (bf16rne(f1.y) << 16);
                o.w = bf16rne(f1.z) | (bf16rne(f1.w) << 16);
            }
            XsU[(n << 4) | (c ^ (n & 15))] = o;
        }
    } else {
        const uint4* X16 = (const uint4*)Xv;
        for (int idx = tid; idx < MT * 16; idx += 256) {
            int n = idx >> 4, c = idx & 15;
            int row = row0 + n;
            uint4 o = make_uint4(0, 0, 0, 0);
            if (row < N) o = X16[(size_t)row * 16 + c];
            XsU[(n << 4) | (c ^ (n & 15))] = o;
        }
    }
    __syncthreads();

    int lane = tid & 63, w = tid >> 6;
    int quad = lane >> 4, l16 = lane & 15;
    const bf16x8* WsF = (const bf16x8*)WsU;
    const bf16x8* XsF = (const bf16x8*)XsU;
    f32x4 acc[8];
    #pragma unroll
    for (int i = 0; i < 8; ++i) acc[i] = (f32x4){0.f, 0.f, 0.f, 0.f};

    int arow = w * 16 + l16;
    #pragma unroll
    for (int ks = 0; ks < 4; ++ks) {
        int c = ks * 4 + quad;
        bf16x8 A = XsF[(arow << 4) | (c ^ l16)];
        #pragma unroll
        for (int nt = 0; nt < 8; ++nt) {
            bf16x8 B = WsF[((nt * 16 + l16) << 4) | (c ^ l16)];
            acc[nt] = __builtin_amdgcn_mfma_f32_16x16x32_bf16(A, B, acc[nt], 0, 0, 0);
        }
    }

    float alv[8], arv[8];
    #pragma unroll
    for (int nt = 0; nt < 8; ++nt) { alv[nt] = al[nt * 16 + l16]; arv[nt] = ar[nt * 16 + l16]; }
    #pragma unroll
    for (int r = 0; r < 4; ++r) {
        float pl = 0.f, pr = 0.f;
        #pragma unroll
        for (int nt = 0; nt < 8; ++nt) { pl += acc[nt][r] * alv[nt]; pr += acc[nt][r] * arv[nt]; }
        #pragma unroll
        for (int o = 1; o < 16; o <<= 1) { pl += __shfl_xor(pl, o); pr += __shfl_xor(pr, o); }
        int row = row0 + w * 16 + quad * 4 + r;
        if (l16 == 0 && row < N) { el[row] = pl; er[row] = pr; }
    }

    unsigned short* XsS = (unsigned short*)XsU;
    #pragma unroll
    for (int nt = 0; nt < 8; ++nt)
        #pragma unroll
        for (int r = 0; r < 4; ++r) {
            int lrow = w * 16 + quad * 4 + r;
            int col = nt * 16 + l16;
            int ch = col >> 3;
            int sc = ch ^ (lrow & 15);
            XsS[lrow * 128 + sc * 8 + (col & 7)] = (unsigned short)bf16rne(acc[nt][r]);
        }
    __syncthreads();
    for (int idx = tid; idx < MT * 16; idx += 256) {
        int n = idx >> 4, c = idx & 15;
        int row = row0 + n;
        if (row < N) ((uint4*)feat16)[(size_t)row * 16 + c] = XsU[(n << 4) | (c ^ (n & 15))];
    }
}

// ---------------- fused edge-softmax + aggregation + bias + relu ----------------

template <bool OUT_BF16>
__global__ __launch_bounds__(256) void k_aggregate(
    const unsigned short* __restrict__ feat16, const float* __restrict__ el,
    const float* __restrict__ er, const int* __restrict__ row_ptr,
    const int* __restrict__ csr_src, const float* __restrict__ bias,
    void* __restrict__ outv, int N) {
    int wid = (blockIdx.x * blockDim.x + threadIdx.x) >> 6;
    int lane = threadIdx.x & 63;
    if (wid >= N) return;
    int beg = row_ptr[wid], end = row_ptr[wid + 1];
    int deg = end - beg;
    float erd = er[wid];

    float m = -INFINITY;
    for (int j = lane; j < deg; j += 64) {
        float e = el[csr_src[beg + j]] + erd;
        e = e >= 0.f ? e : 0.2f * e;
        m = fmaxf(m, e);
    }
    #pragma unroll
    for (int o = 32; o >= 1; o >>= 1) m = fmaxf(m, __shfl_xor(m, o));

    float s = 0.f;
    for (int j = lane; j < deg; j += 64) {
        float e = el[csr_src[beg + j]] + erd;
        e = e >= 0.f ? e : 0.2f * e;
        s += __expf(e - m);
    }
    #pragma unroll
    for (int o = 32; o >= 1; o >>= 1) s += __shfl_xor(s, o);
    float inv = (deg > 0) ? 1.f / s : 0.f;

    int qa = lane >> 4, sub = lane & 15;
    const uint4* f16 = (const uint4*)feat16;
    float acc[8] = {};
    int j = beg + qa;
    for (; j + 4 < end; j += 8) {
        int sn0 = csr_src[j], sn1 = csr_src[j + 4];
        float e0 = el[sn0] + erd; e0 = e0 >= 0.f ? e0 : 0.2f * e0;
        float e1 = el[sn1] + erd; e1 = e1 >= 0.f ? e1 : 0.2f * e1;
        float w0 = __expf(e0 - m) * inv;
        float w1 = __expf(e1 - m) * inv;
        uint4 q0 = f16[(size_t)sn0 * 16 + sub];
        uint4 q1 = f16[(size_t)sn1 * 16 + sub];
        acc[0] += w0 * bflo(q0.x) + w1 * bflo(q1.x);
        acc[1] += w0 * bfhi(q0.x) + w1 * bfhi(q1.x);
        acc[2] += w0 * bflo(q0.y) + w1 * bflo(q1.y);
        acc[3] += w0 * bfhi(q0.y) + w1 * bfhi(q1.y);
        acc[4] += w0 * bflo(q0.z) + w1 * bflo(q1.z);
        acc[5] += w0 * bfhi(q0.z) + w1 * bfhi(q1.z);
        acc[6] += w0 * bflo(q0.w) + w1 * bflo(q1.w);
        acc[7] += w0 * bfhi(q0.w) + w1 * bfhi(q1.w);
    }
    if (j < end) {
        int sn = csr_src[j];
        float e = el[sn] + erd; e = e >= 0.f ? e : 0.2f * e;
        float w = __expf(e - m) * inv;
        uint4 q = f16[(size_t)sn * 16 + sub];
        acc[0] += w * bflo(q.x); acc[1] += w * bfhi(q.x);
        acc[2] += w * bflo(q.y); acc[3] += w * bfhi(q.y);
        acc[4] += w * bflo(q.z); acc[5] += w * bfhi(q.z);
        acc[6] += w * bflo(q.w); acc[7] += w * bfhi(q.w);
    }
    #pragma unroll
    for (int c = 0; c < 8; ++c) {
        acc[c] += __shfl_xor(acc[c], 16);
        acc[c] += __shfl_xor(acc[c], 32);
    }
    if (lane < 16) {
        float4 b0 = ((const float4*)bias)[lane * 2];
        float4 b1 = ((const float4*)bias)[lane * 2 + 1];
        float v[8];
        v[0] = fmaxf(acc[0] + b0.x, 0.f);
        v[1] = fmaxf(acc[1] + b0.y, 0.f);
        v[2] = fmaxf(acc[2] + b0.z, 0.f);
        v[3] = fmaxf(acc[3] + b0.w, 0.f);
        v[4] = fmaxf(acc[4] + b1.x, 0.f);
        v[5] = fmaxf(acc[5] + b1.y, 0.f);
        v[6] = fmaxf(acc[6] + b1.z, 0.f);
        v[7] = fmaxf(acc[7] + b1.w, 0.f);
        if (OUT_BF16) {
            uint4 pk;
            pk.x = bf16rne(v[0]) | (bf16rne(v[1]) << 16);
            pk.y = bf16rne(v[2]) | (bf16rne(v[3]) << 16);
            pk.z = bf16rne(v[4]) | (bf16rne(v[5]) << 16);
            pk.w = bf16rne(v[6]) | (bf16rne(v[7]) << 16);
            ((uint4*)outv)[(size_t)wid * 16 + lane] = pk;
        } else {
            float4 o0 = make_float4(v[0], v[1], v[2], v[3]);
            float4 o1 = make_float4(v[4], v[5], v[6], v[7]);
            ((float4*)outv)[(size_t)wid * 32 + lane * 2] = o0;
            ((float4*)outv)[(size_t)wid * 32 + lane * 2 + 1] = o1;
        }
    }
}

// ---------------- pooling ----------------

__global__ void k_bounds_sorted(const int* __restrict__ gid, int* __restrict__ gs,
                                int* __restrict__ ge, int N) {
    int n = blockIdx.x * blockDim.x + threadIdx.x;
    if (n >= N) return;
    int g = gid[n];
    if (n == 0 || gid[n - 1] != g) gs[g] = n;
    if (n == N - 1 || gid[n + 1] != g) ge[g] = n;
}

__global__ __launch_bounds__(256) void k_pool_partial(const float* __restrict__ x,
                                                      const int* __restrict__ gs,
                                                      const int* __restrict__ ge,
                                                      float* __restrict__ hg) {
    int g = blockIdx.x, c = blockIdx.y;
    int start = gs[g], last = ge[g];
    if (start > last) return;
    int sub = threadIdx.x & 31;
    int r   = threadIdx.x >> 5;
    const float4* x4 = (const float4*)x;
    float4 acc = make_float4(0.f, 0.f, 0.f, 0.f);
    for (int n = start + c * 8 + r; n <= last; n += PCHUNK * 8) {
        float4 v = x4[(size_t)n * 32 + sub];
        acc.x += v.x; acc.y += v.y; acc.z += v.z; acc.w += v.w;
    }
    __shared__ float4 sm[256];
    sm[threadIdx.x] = acc;
    __syncthreads();
    for (int off = 4; off >= 1; off >>= 1) {
        if (r < off) {
            float4 o = sm[threadIdx.x + off * 32];
            float4 v = sm[threadIdx.x];
            v.x += o.x; v.y += o.y; v.z += o.z; v.w += o.w;
            sm[threadIdx.x] = v;
        }
        __syncthreads();
    }
    if (r == 0) {
        float4 v = sm[sub];
        atomicAdd(&hg[g * D + sub * 4 + 0], v.x);
        atomicAdd(&hg[g * D + sub * 4 + 1], v.y);
        atomicAdd(&hg[g * D + sub * 4 + 2], v.z);
        atomicAdd(&hg[g * D + sub * 4 + 3], v.w);
    }
}

__global__ void k_final(const float* __restrict__ hg, const int* __restrict__ gs,
                        const int* __restrict__ ge, const float* __restrict__ Wfc,
                        const float* __restrict__ bfc, float* __restrict__ out) {
    int g = threadIdx.x;
    if (g >= NUM_GRAPHS) return;
    int start = gs[g], last = ge[g];
    float cnt = (start <= last) ? (float)(last - start + 1) : 1.f;
    float ic = 1.f / cnt;
    float l0 = bfc[0], l1 = bfc[1];
    for (int d = 0; d < D; d++) {
        float v = hg[g * D + d] * ic;
        l0 += v * Wfc[2 * d];
        l1 += v * Wfc[2 * d + 1];
    }
    float mm = fmaxf(l0, l1);
    float lse = mm + logf(expf(l0 - mm) + expf(l1 - mm));
    out[2 * g] = l0 - lse;
    out[2 * g + 1] = l1 - lse;
}

// ---------------- launch ----------------

extern "C" void kernel_launch(void* const* d_in, const int* in_sizes, int n_in,
                              void* d_out, int out_size, void* d_ws, size_t ws_size,
                              hipStream_t stream) {
    const float* h   = (const float*)d_in[0];
    const int* src   = (const int*)d_in[1];
    const int* dst   = (const int*)d_in[2];
    const int* gid   = (const int*)d_in[3];
    const float* W1  = (const float*)d_in[4];
    const float* al1 = (const float*)d_in[5];
    const float* ar1 = (const float*)d_in[6];
    const float* b1  = (const float*)d_in[7];
    const float* W2  = (const float*)d_in[8];
    const float* al2 = (const float*)d_in[9];
    const float* ar2 = (const float*)d_in[10];
    const float* b2  = (const float*)d_in[11];
    const float* Wfc = (const float*)d_in[12];
    const float* bfc = (const float*)d_in[13];
    float* out = (float*)d_out;

    int N = in_sizes[0] / D;
    int E = in_sizes[1];
    int NB = (N + 127) >> 7;   // <= 1024 for N <= 131072 (17-bit src pack)

    char* p = (char*)d_ws;
    unsigned short* feat16  = (unsigned short*)p; p += (size_t)N * D * 2;
    unsigned short* featAgg = (unsigned short*)p; p += (size_t)N * D * 2;
    float* featB = (float*)p; p += (size_t)N * D * 4;
    float* el    = (float*)p; p += (size_t)N * 4;
    float* er    = (float*)p; p += (size_t)N * 4;
    int* row_ptr = (int*)p;   p += (size_t)(N + 4) * 4;
    int* csr_src = (int*)p;   p += (size_t)E * 4;
    unsigned* part = (unsigned*)p; p += (size_t)E * 4;
    int* bhist   = (int*)p;   p += 1028 * 4;
    int* bbase   = (int*)p;   p += 1028 * 4;
    int* bcur    = (int*)p;   p += 1028 * 4;
    int* gs      = (int*)p;   p += NUM_GRAPHS * 4;
    int* ge      = (int*)p;   p += NUM_GRAPHS * 4;
    float* hg    = (float*)p; p += NUM_GRAPHS * D * 4;
    unsigned short* Wt1 = (unsigned short*)p; p += D * D * 2;
    unsigned short* Wt2 = (unsigned short*)p; p += D * D * 2;

    int nbN = (N + 255) / 256;
    int nbW = (N * 64 + 255) / 256;
    int nbT = (E + ETILE - 1) / ETILE;
    int gemmB = (N + MT - 1) / MT;

    hipMemsetAsync(bhist, 0, (size_t)NB * 4, stream);
    hipMemsetAsync(gs, 0x7f, NUM_GRAPHS * 4, stream);
    hipMemsetAsync(ge, 0xff, NUM_GRAPHS * 4, stream);
    hipMemsetAsync(hg, 0, NUM_GRAPHS * D * 4, stream);

    // bucket partition of edges (replaces global histo + N-scan + scatter fill)
    k_prep_w<<<dim3(8, 2), 256, 0, stream>>>(W1, W2, Wt1, Wt2);
    k_bucket_hist<<<nbT, 256, 0, stream>>>(dst, bhist, E);
    k_bucket_scan<<<1, 1024, 0, stream>>>(bhist, bbase, bcur, NB, E, row_ptr, N);
    k_partition<<<nbT, 256, 0, stream>>>(src, dst, bcur, part, E);

    // Layer 1: MFMA GEMM (fp32 in) + el/er + bf16 out, overlapped with bucket->CSR
    k_gemm_mfma_sort<<<gemmB + NB, 256, 0, stream>>>(
        h, 1, Wt1, al1, ar1, feat16, el, er, N, gemmB,
        part, bbase, row_ptr, csr_src);
    k_aggregate<true><<<nbW, 256, 0, stream>>>(feat16, el, er, row_ptr, csr_src,
                                               b1, featAgg, N);

    // Layer 2: MFMA GEMM (bf16 in), all blocks gemm role
    k_gemm_mfma_sort<<<gemmB, 256, 0, stream>>>(
        featAgg, 0, Wt2, al2, ar2, feat16, el, er, N, gemmB,
        part, bbase, row_ptr, csr_src);
    k_aggregate<false><<<nbW, 256, 0, stream>>>(feat16, el, er, row_ptr, csr_src,
                                                b2, featB, N);

    // Pool + FC + log_softmax
    k_bounds_sorted<<<nbN, 256, 0, stream>>>(gid, gs, ge, N);
    k_pool_partial<<<dim3(NUM_GRAPHS, PCHUNK), 256, 0, stream>>>(featB, gs, ge, hg);
    k_final<<<1, 64, 0, stream>>>(hg, gs, ge, Wfc, bfc, out);
}

// Round 7
// 366.524 us; speedup vs baseline: 4.2203x; 1.1040x over previous
//
#include <hip/hip_runtime.h>
#include <math.h>

#define NUM_GRAPHS 64
#define D 128
#define PCHUNK 16
#define MT 64      // GEMM rows per block
#define ETILE 4096 // edges per partition block

typedef __attribute__((ext_vector_type(8))) short bf16x8;
typedef __attribute__((ext_vector_type(4))) float f32x4;

__device__ __forceinline__ unsigned bf16rne(float x) {
    unsigned u = __float_as_uint(x);
    return (u + 0x7fffu + ((u >> 16) & 1u)) >> 16;
}
__device__ __forceinline__ float bflo(unsigned u) { return __uint_as_float(u << 16); }
__device__ __forceinline__ float bfhi(unsigned u) { return __uint_as_float(u & 0xffff0000u); }

// ---------------- bucket CSR build (counting sort, LDS-local) ----------------

__global__ __launch_bounds__(256) void k_bucket_hist(const int* __restrict__ dst,
                                                     int* __restrict__ bhist, int E) {
    __shared__ int h[1024];
    int tid = threadIdx.x;
    for (int i = tid; i < 1024; i += 256) h[i] = 0;
    __syncthreads();
    int e0 = blockIdx.x * ETILE;
    int e1 = min(e0 + ETILE, E);
    for (int i = e0 + tid; i < e1; i += 256) atomicAdd(&h[dst[i] >> 7], 1);
    __syncthreads();
    for (int i = tid; i < 1024; i += 256)
        if (h[i]) atomicAdd(&bhist[i], h[i]);
}

__global__ __launch_bounds__(1024) void k_bucket_scan(const int* __restrict__ bhist,
                                                      int* __restrict__ bbase,
                                                      int* __restrict__ bcur,
                                                      int NB, int E,
                                                      int* __restrict__ row_ptr, int N) {
    __shared__ int sm[1024];
    int t = threadIdx.x;
    int v = (t < NB) ? bhist[t] : 0;
    sm[t] = v;
    __syncthreads();
    for (int off = 1; off < 1024; off <<= 1) {
        int y = (t >= off) ? sm[t - off] : 0;
        __syncthreads();
        sm[t] += y;
        __syncthreads();
    }
    if (t < NB) { bbase[t] = sm[t] - v; bcur[t] = sm[t] - v; }
    if (t == 0) { bbase[NB] = E; row_ptr[N] = E; }
}

__global__ __launch_bounds__(256) void k_partition(const int* __restrict__ src,
                                                   const int* __restrict__ dst,
                                                   int* __restrict__ bcur,
                                                   unsigned* __restrict__ part, int E) {
    __shared__ int h[1024];
    __shared__ int cur[1024];
    int tid = threadIdx.x;
    for (int i = tid; i < 1024; i += 256) h[i] = 0;
    __syncthreads();
    int e0 = blockIdx.x * ETILE;
    int e1 = min(e0 + ETILE, E);
    for (int i = e0 + tid; i < e1; i += 256) atomicAdd(&h[dst[i] >> 7], 1);
    __syncthreads();
    for (int i = tid; i < 1024; i += 256) {
        int c = h[i];
        cur[i] = c ? atomicAdd(&bcur[i], c) : 0;
    }
    __syncthreads();
    for (int i = e0 + tid; i < e1; i += 256) {
        int d = dst[i];
        int b = d >> 7;
        int pos = atomicAdd(&cur[b], 1);
        part[pos] = (unsigned)src[i] | ((unsigned)(d & 127) << 17);
    }
}

// ---------------- W -> transposed bf16 (Wt[n][k]) ----------------

__global__ void k_prep_w(const float* __restrict__ W1, const float* __restrict__ W2,
                         unsigned short* __restrict__ Wt1, unsigned short* __restrict__ Wt2) {
    const float* W = blockIdx.y ? W2 : W1;
    unsigned short* Wt = blockIdx.y ? Wt2 : Wt1;
    int n = blockIdx.x * 16 + (threadIdx.x >> 4);
    int c = threadIdx.x & 15;
    unsigned v[8];
    #pragma unroll
    for (int j = 0; j < 8; ++j) v[j] = bf16rne(W[(c * 8 + j) * D + n]);
    uint4 pk;
    pk.x = v[0] | (v[1] << 16);
    pk.y = v[2] | (v[3] << 16);
    pk.z = v[4] | (v[5] << 16);
    pk.w = v[6] | (v[7] << 16);
    ((uint4*)Wt)[n * 16 + c] = pk;
}

// ---------------- MFMA GEMM (+el/er+blockmax, bf16 out) fused with bucket->CSR --------

__global__ __launch_bounds__(256) void k_gemm_mfma_sort(
    const void* __restrict__ Xv, int x_fp32,
    const unsigned short* __restrict__ Wt16,
    const float* __restrict__ al, const float* __restrict__ ar,
    unsigned short* __restrict__ feat16, float* __restrict__ el,
    float* __restrict__ er, float* __restrict__ blockmax, int N, int gemmBlocks,
    const unsigned* __restrict__ part, const int* __restrict__ bbase,
    int* __restrict__ row_ptr, int* __restrict__ csr_src) {
    __shared__ uint4 WsU[128 * 16];  // 32 KB
    __shared__ uint4 XsU[MT * 16];   // 16 KB
    __shared__ float smax[4];
    int bx = blockIdx.x;
    int T = gridDim.x;
    int g0 = (int)((long long)bx * gemmBlocks / T);
    int g1 = (int)((long long)(bx + 1) * gemmBlocks / T);
    int tid = threadIdx.x;

    if (g1 == g0) {
        // ---- sort role: bucket -> CSR ----
        int b = bx - g0;
        int base = bbase[b];
        int bcnt = bbase[b + 1] - base;
        int* ldeg = (int*)XsU;
        int* lcur = ldeg + 128;
        if (tid < 128) ldeg[tid] = 0;
        __syncthreads();
        for (int i = tid; i < bcnt; i += 256)
            atomicAdd(&ldeg[part[base + i] >> 17], 1);
        __syncthreads();
        int myv = (tid < 128) ? ldeg[tid] : 0;
        for (int off = 1; off < 128; off <<= 1) {
            int y = 0;
            if (tid < 128 && tid >= off) y = ldeg[tid - off];
            __syncthreads();
            if (tid < 128) ldeg[tid] += y;
            __syncthreads();
        }
        if (tid < 128) {
            int excl = ldeg[tid] - myv;
            int node = (b << 7) + tid;
            if (node < N) row_ptr[node] = base + excl;
            lcur[tid] = base + excl;
        }
        __syncthreads();
        for (int i = tid; i < bcnt; i += 256) {
            unsigned v = part[base + i];
            int pos = atomicAdd(&lcur[v >> 17], 1);
            csr_src[pos] = (int)(v & 0x1FFFFu);
        }
        return;
    }

    // ---- gemm role ----
    int row0 = g0 * MT;

    for (int idx = tid; idx < 128 * 16; idx += 256) {
        int n = idx >> 4, c = idx & 15;
        WsU[(n << 4) | (c ^ (n & 15))] = ((const uint4*)Wt16)[idx];
    }
    if (x_fp32) {
        const float4* X4 = (const float4*)Xv;
        for (int idx = tid; idx < MT * 16; idx += 256) {
            int n = idx >> 4, c = idx & 15;
            int row = row0 + n;
            uint4 o = make_uint4(0, 0, 0, 0);
            if (row < N) {
                float4 f0 = X4[(size_t)row * 32 + c * 2];
                float4 f1 = X4[(size_t)row * 32 + c * 2 + 1];
                o.x = bf16rne(f0.x) | (bf16rne(f0.y) << 16);
                o.y = bf16rne(f0.z) | (bf16rne(f0.w) << 16);
                o.z = bf16rne(f1.x) | (bf16rne(f1.y) << 16);
                o.w = bf16rne(f1.z) | (bf16rne(f1.w) << 16);
            }
            XsU[(n << 4) | (c ^ (n & 15))] = o;
        }
    } else {
        const uint4* X16 = (const uint4*)Xv;
        for (int idx = tid; idx < MT * 16; idx += 256) {
            int n = idx >> 4, c = idx & 15;
            int row = row0 + n;
            uint4 o = make_uint4(0, 0, 0, 0);
            if (row < N) o = X16[(size_t)row * 16 + c];
            XsU[(n << 4) | (c ^ (n & 15))] = o;
        }
    }
    __syncthreads();

    int lane = tid & 63, w = tid >> 6;
    int quad = lane >> 4, l16 = lane & 15;
    const bf16x8* WsF = (const bf16x8*)WsU;
    const bf16x8* XsF = (const bf16x8*)XsU;
    f32x4 acc[8];
    #pragma unroll
    for (int i = 0; i < 8; ++i) acc[i] = (f32x4){0.f, 0.f, 0.f, 0.f};

    int arow = w * 16 + l16;
    #pragma unroll
    for (int ks = 0; ks < 4; ++ks) {
        int c = ks * 4 + quad;
        bf16x8 A = XsF[(arow << 4) | (c ^ l16)];
        #pragma unroll
        for (int nt = 0; nt < 8; ++nt) {
            bf16x8 B = WsF[((nt * 16 + l16) << 4) | (c ^ l16)];
            acc[nt] = __builtin_amdgcn_mfma_f32_16x16x32_bf16(A, B, acc[nt], 0, 0, 0);
        }
    }

    // el/er epilogue + running el-max (for the global softmax shift)
    float alv[8], arv[8];
    #pragma unroll
    for (int nt = 0; nt < 8; ++nt) { alv[nt] = al[nt * 16 + l16]; arv[nt] = ar[nt * 16 + l16]; }
    float lmax = -1e30f;
    #pragma unroll
    for (int r = 0; r < 4; ++r) {
        float pl = 0.f, pr = 0.f;
        #pragma unroll
        for (int nt = 0; nt < 8; ++nt) { pl += acc[nt][r] * alv[nt]; pr += acc[nt][r] * arv[nt]; }
        #pragma unroll
        for (int o = 1; o < 16; o <<= 1) { pl += __shfl_xor(pl, o); pr += __shfl_xor(pr, o); }
        int row = row0 + w * 16 + quad * 4 + r;
        if (l16 == 0 && row < N) { el[row] = pl; er[row] = pr; }
        lmax = fmaxf(lmax, pl);
    }
    lmax = fmaxf(lmax, __shfl_xor(lmax, 16));
    lmax = fmaxf(lmax, __shfl_xor(lmax, 32));
    if (lane == 0) smax[w] = lmax;

    unsigned short* XsS = (unsigned short*)XsU;
    #pragma unroll
    for (int nt = 0; nt < 8; ++nt)
        #pragma unroll
        for (int r = 0; r < 4; ++r) {
            int lrow = w * 16 + quad * 4 + r;
            int col = nt * 16 + l16;
            int ch = col >> 3;
            int sc = ch ^ (lrow & 15);
            XsS[lrow * 128 + sc * 8 + (col & 7)] = (unsigned short)bf16rne(acc[nt][r]);
        }
    __syncthreads();
    if (tid == 0)
        blockmax[g0] = fmaxf(fmaxf(smax[0], smax[1]), fmaxf(smax[2], smax[3]));
    for (int idx = tid; idx < MT * 16; idx += 256) {
        int n = idx >> 4, c = idx & 15;
        int row = row0 + n;
        if (row < N) ((uint4*)feat16)[(size_t)row * 16 + c] = XsU[(n << 4) | (c ^ (n & 15))];
    }
}

__global__ void k_foldmax(const float* __restrict__ blockmax, int n,
                          float* __restrict__ glmax) {
    float m = -1e30f;
    for (int i = threadIdx.x; i < n; i += 256) m = fmaxf(m, blockmax[i]);
    #pragma unroll
    for (int o = 32; o >= 1; o >>= 1) m = fmaxf(m, __shfl_xor(m, o));
    __shared__ float sm[4];
    if ((threadIdx.x & 63) == 0) sm[threadIdx.x >> 6] = m;
    __syncthreads();
    if (threadIdx.x == 0)
        glmax[0] = fmaxf(fmaxf(sm[0], sm[1]), fmaxf(sm[2], sm[3]));
}

// ---------------- single-pass edge-softmax + aggregation (global-max shift) --------
// M_d = LR(EL* + er_d) >= per-dst max since LeakyReLU is monotone and er_d is
// per-dst constant. One pass: s += ex, acc += ex*f; out = acc/s + b, ReLU, bf16.

__global__ __launch_bounds__(256) void k_aggregate(
    const unsigned short* __restrict__ feat16, const float* __restrict__ el,
    const float* __restrict__ er, const int* __restrict__ row_ptr,
    const int* __restrict__ csr_src, const float* __restrict__ bias,
    const float* __restrict__ glmax, unsigned short* __restrict__ outv, int N) {
    int wid = (blockIdx.x * blockDim.x + threadIdx.x) >> 6;
    int lane = threadIdx.x & 63;
    if (wid >= N) return;
    int beg = row_ptr[wid], end = row_ptr[wid + 1];
    float erd = er[wid];
    float M = glmax[0] + erd;
    M = M >= 0.f ? M : 0.2f * M;

    int qa = lane >> 4, sub = lane & 15;
    const uint4* f16 = (const uint4*)feat16;
    float acc[8] = {};
    float s = 0.f;
    int j = beg + qa;
    for (; j + 4 < end; j += 8) {
        int sn0 = csr_src[j], sn1 = csr_src[j + 4];
        float e0 = el[sn0] + erd; e0 = e0 >= 0.f ? e0 : 0.2f * e0;
        float e1 = el[sn1] + erd; e1 = e1 >= 0.f ? e1 : 0.2f * e1;
        float w0 = __expf(e0 - M);
        float w1 = __expf(e1 - M);
        uint4 q0 = f16[(size_t)sn0 * 16 + sub];
        uint4 q1 = f16[(size_t)sn1 * 16 + sub];
        s += w0 + w1;
        acc[0] += w0 * bflo(q0.x) + w1 * bflo(q1.x);
        acc[1] += w0 * bfhi(q0.x) + w1 * bfhi(q1.x);
        acc[2] += w0 * bflo(q0.y) + w1 * bflo(q1.y);
        acc[3] += w0 * bfhi(q0.y) + w1 * bfhi(q1.y);
        acc[4] += w0 * bflo(q0.z) + w1 * bflo(q1.z);
        acc[5] += w0 * bfhi(q0.z) + w1 * bfhi(q1.z);
        acc[6] += w0 * bflo(q0.w) + w1 * bflo(q1.w);
        acc[7] += w0 * bfhi(q0.w) + w1 * bfhi(q1.w);
    }
    if (j < end) {
        int sn = csr_src[j];
        float e = el[sn] + erd; e = e >= 0.f ? e : 0.2f * e;
        float w = __expf(e - M);
        uint4 q = f16[(size_t)sn * 16 + sub];
        s += w;
        acc[0] += w * bflo(q.x); acc[1] += w * bfhi(q.x);
        acc[2] += w * bflo(q.y); acc[3] += w * bfhi(q.y);
        acc[4] += w * bflo(q.z); acc[5] += w * bfhi(q.z);
        acc[6] += w * bflo(q.w); acc[7] += w * bfhi(q.w);
    }
    #pragma unroll
    for (int c = 0; c < 8; ++c) {
        acc[c] += __shfl_xor(acc[c], 16);
        acc[c] += __shfl_xor(acc[c], 32);
    }
    s += __shfl_xor(s, 16);
    s += __shfl_xor(s, 32);
    float inv = (end > beg) ? 1.f / s : 0.f;
    if (lane < 16) {
        float4 b0 = ((const float4*)bias)[lane * 2];
        float4 b1 = ((const float4*)bias)[lane * 2 + 1];
        float v[8];
        v[0] = fmaxf(acc[0] * inv + b0.x, 0.f);
        v[1] = fmaxf(acc[1] * inv + b0.y, 0.f);
        v[2] = fmaxf(acc[2] * inv + b0.z, 0.f);
        v[3] = fmaxf(acc[3] * inv + b0.w, 0.f);
        v[4] = fmaxf(acc[4] * inv + b1.x, 0.f);
        v[5] = fmaxf(acc[5] * inv + b1.y, 0.f);
        v[6] = fmaxf(acc[6] * inv + b1.z, 0.f);
        v[7] = fmaxf(acc[7] * inv + b1.w, 0.f);
        uint4 pk;
        pk.x = bf16rne(v[0]) | (bf16rne(v[1]) << 16);
        pk.y = bf16rne(v[2]) | (bf16rne(v[3]) << 16);
        pk.z = bf16rne(v[4]) | (bf16rne(v[5]) << 16);
        pk.w = bf16rne(v[6]) | (bf16rne(v[7]) << 16);
        ((uint4*)outv)[(size_t)wid * 16 + lane] = pk;
    }
}

// ---------------- pooling ----------------

__global__ void k_bounds_sorted(const int* __restrict__ gid, int* __restrict__ gs,
                                int* __restrict__ ge, int N) {
    int n = blockIdx.x * blockDim.x + threadIdx.x;
    if (n >= N) return;
    int g = gid[n];
    if (n == 0 || gid[n - 1] != g) gs[g] = n;
    if (n == N - 1 || gid[n + 1] != g) ge[g] = n;
}

// bf16 input: block = 16 row slots x 16 ch threads (uint4 = 8 bf16 ch each).
__global__ __launch_bounds__(256) void k_pool_partial(const unsigned short* __restrict__ x,
                                                      const int* __restrict__ gs,
                                                      const int* __restrict__ ge,
                                                      float* __restrict__ hg) {
    int g = blockIdx.x, c = blockIdx.y;
    int start = gs[g], last = ge[g];
    if (start > last) return;
    int sub = threadIdx.x & 15;
    int r   = threadIdx.x >> 4;
    const uint4* x4 = (const uint4*)x;
    float acc[8] = {};
    for (int n = start + c * 16 + r; n <= last; n += PCHUNK * 16) {
        uint4 q = x4[(size_t)n * 16 + sub];
        acc[0] += bflo(q.x); acc[1] += bfhi(q.x);
        acc[2] += bflo(q.y); acc[3] += bfhi(q.y);
        acc[4] += bflo(q.z); acc[5] += bfhi(q.z);
        acc[6] += bflo(q.w); acc[7] += bfhi(q.w);
    }
    __shared__ float sm[256][8];
    #pragma unroll
    for (int k = 0; k < 8; ++k) sm[threadIdx.x][k] = acc[k];
    __syncthreads();
    for (int off = 8; off >= 1; off >>= 1) {
        if (r < off) {
            #pragma unroll
            for (int k = 0; k < 8; ++k)
                sm[threadIdx.x][k] += sm[threadIdx.x + off * 16][k];
        }
        __syncthreads();
    }
    if (r == 0) {
        #pragma unroll
        for (int k = 0; k < 8; ++k)
            atomicAdd(&hg[g * D + sub * 8 + k], sm[sub][k]);
    }
}

__global__ void k_final(const float* __restrict__ hg, const int* __restrict__ gs,
                        const int* __restrict__ ge, const float* __restrict__ Wfc,
                        const float* __restrict__ bfc, float* __restrict__ out) {
    int g = threadIdx.x;
    if (g >= NUM_GRAPHS) return;
    int start = gs[g], last = ge[g];
    float cnt = (start <= last) ? (float)(last - start + 1) : 1.f;
    float ic = 1.f / cnt;
    float l0 = bfc[0], l1 = bfc[1];
    for (int d = 0; d < D; d++) {
        float v = hg[g * D + d] * ic;
        l0 += v * Wfc[2 * d];
        l1 += v * Wfc[2 * d + 1];
    }
    float mm = fmaxf(l0, l1);
    float lse = mm + logf(expf(l0 - mm) + expf(l1 - mm));
    out[2 * g] = l0 - lse;
    out[2 * g + 1] = l1 - lse;
}

// ---------------- launch ----------------

extern "C" void kernel_launch(void* const* d_in, const int* in_sizes, int n_in,
                              void* d_out, int out_size, void* d_ws, size_t ws_size,
                              hipStream_t stream) {
    const float* h   = (const float*)d_in[0];
    const int* src   = (const int*)d_in[1];
    const int* dst   = (const int*)d_in[2];
    const int* gid   = (const int*)d_in[3];
    const float* W1  = (const float*)d_in[4];
    const float* al1 = (const float*)d_in[5];
    const float* ar1 = (const float*)d_in[6];
    const float* b1  = (const float*)d_in[7];
    const float* W2  = (const float*)d_in[8];
    const float* al2 = (const float*)d_in[9];
    const float* ar2 = (const float*)d_in[10];
    const float* b2  = (const float*)d_in[11];
    const float* Wfc = (const float*)d_in[12];
    const float* bfc = (const float*)d_in[13];
    float* out = (float*)d_out;

    int N = in_sizes[0] / D;
    int E = in_sizes[1];
    int NB = (N + 127) >> 7;

    char* p = (char*)d_ws;
    unsigned short* feat16  = (unsigned short*)p; p += (size_t)N * D * 2;  // GEMM out
    unsigned short* featAgg = (unsigned short*)p; p += (size_t)N * D * 2;  // agg out (bf16)
    float* el    = (float*)p; p += (size_t)N * 4;
    float* er    = (float*)p; p += (size_t)N * 4;
    int* row_ptr = (int*)p;   p += (size_t)(N + 4) * 4;
    int* csr_src = (int*)p;   p += (size_t)E * 4;
    unsigned* part = (unsigned*)p; p += (size_t)E * 4;
    int* bhist   = (int*)p;   p += 1028 * 4;
    int* bbase   = (int*)p;   p += 1028 * 4;
    int* bcur    = (int*)p;   p += 1028 * 4;
    int* gs      = (int*)p;   p += NUM_GRAPHS * 4;
    int* ge      = (int*)p;   p += NUM_GRAPHS * 4;
    float* hg    = (float*)p; p += NUM_GRAPHS * D * 4;
    unsigned short* Wt1 = (unsigned short*)p; p += D * D * 2;
    unsigned short* Wt2 = (unsigned short*)p; p += D * D * 2;
    float* blockmax = (float*)p; p += (size_t)((N + MT - 1) / MT + 4) * 4;
    float* glmax = (float*)p; p += 4 * 4;

    int nbN = (N + 255) / 256;
    int nbW = (N * 64 + 255) / 256;
    int nbT = (E + ETILE - 1) / ETILE;
    int gemmB = (N + MT - 1) / MT;

    hipMemsetAsync(bhist, 0, (size_t)NB * 4, stream);
    hipMemsetAsync(gs, 0x7f, NUM_GRAPHS * 4, stream);
    hipMemsetAsync(ge, 0xff, NUM_GRAPHS * 4, stream);
    hipMemsetAsync(hg, 0, NUM_GRAPHS * D * 4, stream);

    k_prep_w<<<dim3(8, 2), 256, 0, stream>>>(W1, W2, Wt1, Wt2);
    k_bucket_hist<<<nbT, 256, 0, stream>>>(dst, bhist, E);
    k_bucket_scan<<<1, 1024, 0, stream>>>(bhist, bbase, bcur, NB, E, row_ptr, N);
    k_partition<<<nbT, 256, 0, stream>>>(src, dst, bcur, part, E);

    // Layer 1: MFMA GEMM (fp32 in) + el/er + blockmax, overlapped with bucket->CSR
    k_gemm_mfma_sort<<<gemmB + NB, 256, 0, stream>>>(
        h, 1, Wt1, al1, ar1, feat16, el, er, blockmax, N, gemmB,
        part, bbase, row_ptr, csr_src);
    k_foldmax<<<1, 256, 0, stream>>>(blockmax, gemmB, glmax);
    k_aggregate<<<nbW, 256, 0, stream>>>(feat16, el, er, row_ptr, csr_src,
                                         b1, glmax, featAgg, N);

    // Layer 2: MFMA GEMM (bf16 in), all blocks gemm role
    k_gemm_mfma_sort<<<gemmB, 256, 0, stream>>>(
        featAgg, 0, Wt2, al2, ar2, feat16, el, er, blockmax, N, gemmB,
        part, bbase, row_ptr, csr_src);
    k_foldmax<<<1, 256, 0, stream>>>(blockmax, gemmB, glmax);
    k_aggregate<<<nbW, 256, 0, stream>>>(feat16, el, er, row_ptr, csr_src,
                                         b2, glmax, featAgg, N);

    // Pool + FC + log_softmax
    k_bounds_sorted<<<nbN, 256, 0, stream>>>(gid, gs, ge, N);
    k_pool_partial<<<dim3(NUM_GRAPHS, PCHUNK), 256, 0, stream>>>(featAgg, gs, ge, hg);
    k_final<<<1, 64, 0, stream>>>(hg, gs, ge, Wfc, bfc, out);
}

// Round 8
// 355.917 us; speedup vs baseline: 4.3460x; 1.0298x over previous
//
#include <hip/hip_runtime.h>
#include <math.h>

#define NUM_GRAPHS 64
#define D 128
#define PCHUNK 16
#define MT 64      // GEMM rows per block
#define ETILE 4096 // edges per partition block

typedef __attribute__((ext_vector_type(8))) short bf16x8;
typedef __attribute__((ext_vector_type(4))) float f32x4;
typedef __attribute__((ext_vector_type(2))) float f32x2;

__device__ __forceinline__ unsigned bf16rne(float x) {
    unsigned u = __float_as_uint(x);
    return (u + 0x7fffu + ((u >> 16) & 1u)) >> 16;
}
__device__ __forceinline__ float bflo(unsigned u) { return __uint_as_float(u << 16); }
__device__ __forceinline__ float bfhi(unsigned u) { return __uint_as_float(u & 0xffff0000u); }

// monotone float <-> uint order-preserving encoding (for atomicMax on float)
__device__ __forceinline__ unsigned encf(float f) {
    unsigned u = __float_as_uint(f);
    return (u & 0x80000000u) ? ~u : (u | 0x80000000u);
}
__device__ __forceinline__ float decf(unsigned e) {
    unsigned u = (e & 0x80000000u) ? (e & 0x7fffffffu) : ~e;
    return __uint_as_float(u);
}

// ---------------- front kernel: bucket hist + weight prep + graph bounds ----------------

__global__ __launch_bounds__(256) void k_front(
    const int* __restrict__ dst, int* __restrict__ bhist, int E, int nbT,
    const float* __restrict__ W1, const float* __restrict__ W2,
    unsigned short* __restrict__ Wt1, unsigned short* __restrict__ Wt2,
    const int* __restrict__ gid, int* __restrict__ gs, int* __restrict__ ge, int N) {
    __shared__ int h[1024];
    int b = blockIdx.x;
    int tid = threadIdx.x;
    if (b < nbT) {
        // ---- histogram role ----
        for (int i = tid; i < 1024; i += 256) h[i] = 0;
        __syncthreads();
        int e0 = b * ETILE;
        int e1 = min(e0 + ETILE, E);
        for (int i = e0 + tid; i < e1; i += 256) atomicAdd(&h[dst[i] >> 7], 1);
        __syncthreads();
        for (int i = tid; i < 1024; i += 256)
            if (h[i]) atomicAdd(&bhist[i], h[i]);
    } else if (b < nbT + 16) {
        // ---- weight transpose role (bf16, Wt[n][k]) ----
        int bb = b - nbT;
        const float* W = (bb & 8) ? W2 : W1;
        unsigned short* Wt = (bb & 8) ? Wt2 : Wt1;
        int n = (bb & 7) * 16 + (tid >> 4);
        int c = tid & 15;
        unsigned v[8];
        #pragma unroll
        for (int j = 0; j < 8; ++j) v[j] = bf16rne(W[(c * 8 + j) * D + n]);
        uint4 pk;
        pk.x = v[0] | (v[1] << 16);
        pk.y = v[2] | (v[3] << 16);
        pk.z = v[4] | (v[5] << 16);
        pk.w = v[6] | (v[7] << 16);
        ((uint4*)Wt)[n * 16 + c] = pk;
    } else {
        // ---- graph bounds role (gid sorted -> contiguous ranges) ----
        int n = (b - nbT - 16) * 256 + tid;
        if (n >= N) return;
        int g = gid[n];
        if (n == 0 || gid[n - 1] != g) gs[g] = n;
        if (n == N - 1 || gid[n + 1] != g) ge[g] = n;
    }
}

__global__ __launch_bounds__(1024) void k_bucket_scan(const int* __restrict__ bhist,
                                                      int* __restrict__ bbase,
                                                      int* __restrict__ bcur,
                                                      int NB, int E,
                                                      int* __restrict__ row_ptr, int N) {
    __shared__ int sm[1024];
    int t = threadIdx.x;
    int v = (t < NB) ? bhist[t] : 0;
    sm[t] = v;
    __syncthreads();
    for (int off = 1; off < 1024; off <<= 1) {
        int y = (t >= off) ? sm[t - off] : 0;
        __syncthreads();
        sm[t] += y;
        __syncthreads();
    }
    if (t < NB) { bbase[t] = sm[t] - v; bcur[t] = sm[t] - v; }
    if (t == 0) { bbase[NB] = E; row_ptr[N] = E; }
}

__global__ __launch_bounds__(256) void k_partition(const int* __restrict__ src,
                                                   const int* __restrict__ dst,
                                                   int* __restrict__ bcur,
                                                   unsigned* __restrict__ part, int E) {
    __shared__ int h[1024];
    __shared__ int cur[1024];
    int tid = threadIdx.x;
    for (int i = tid; i < 1024; i += 256) h[i] = 0;
    __syncthreads();
    int e0 = blockIdx.x * ETILE;
    int e1 = min(e0 + ETILE, E);
    for (int i = e0 + tid; i < e1; i += 256) atomicAdd(&h[dst[i] >> 7], 1);
    __syncthreads();
    for (int i = tid; i < 1024; i += 256) {
        int c = h[i];
        cur[i] = c ? atomicAdd(&bcur[i], c) : 0;
    }
    __syncthreads();
    for (int i = e0 + tid; i < e1; i += 256) {
        int d = dst[i];
        int b = d >> 7;
        int pos = atomicAdd(&cur[b], 1);
        part[pos] = (unsigned)src[i] | ((unsigned)(d & 127) << 17);
    }
}

// ---------------- MFMA GEMM (+el/er + atomic global el-max) fused with bucket->CSR -----

__global__ __launch_bounds__(256) void k_gemm_mfma_sort(
    const void* __restrict__ Xv, int x_fp32,
    const unsigned short* __restrict__ Wt16,
    const float* __restrict__ al, const float* __restrict__ ar,
    unsigned short* __restrict__ feat16, float* __restrict__ el,
    float* __restrict__ er, unsigned* __restrict__ glmax_u, int N, int gemmBlocks,
    const unsigned* __restrict__ part, const int* __restrict__ bbase,
    int* __restrict__ row_ptr, int* __restrict__ csr_src) {
    __shared__ uint4 WsU[128 * 16];  // 32 KB
    __shared__ uint4 XsU[MT * 16];   // 16 KB
    __shared__ float smax[4];
    int bx = blockIdx.x;
    int T = gridDim.x;
    int g0 = (int)((long long)bx * gemmBlocks / T);
    int g1 = (int)((long long)(bx + 1) * gemmBlocks / T);
    int tid = threadIdx.x;

    if (g1 == g0) {
        // ---- sort role: bucket -> CSR ----
        int b = bx - g0;
        int base = bbase[b];
        int bcnt = bbase[b + 1] - base;
        int* ldeg = (int*)XsU;
        int* lcur = ldeg + 128;
        if (tid < 128) ldeg[tid] = 0;
        __syncthreads();
        for (int i = tid; i < bcnt; i += 256)
            atomicAdd(&ldeg[part[base + i] >> 17], 1);
        __syncthreads();
        int myv = (tid < 128) ? ldeg[tid] : 0;
        for (int off = 1; off < 128; off <<= 1) {
            int y = 0;
            if (tid < 128 && tid >= off) y = ldeg[tid - off];
            __syncthreads();
            if (tid < 128) ldeg[tid] += y;
            __syncthreads();
        }
        if (tid < 128) {
            int excl = ldeg[tid] - myv;
            int node = (b << 7) + tid;
            if (node < N) row_ptr[node] = base + excl;
            lcur[tid] = base + excl;
        }
        __syncthreads();
        for (int i = tid; i < bcnt; i += 256) {
            unsigned v = part[base + i];
            int pos = atomicAdd(&lcur[v >> 17], 1);
            csr_src[pos] = (int)(v & 0x1FFFFu);
        }
        return;
    }

    // ---- gemm role ----
    int row0 = g0 * MT;

    for (int idx = tid; idx < 128 * 16; idx += 256) {
        int n = idx >> 4, c = idx & 15;
        WsU[(n << 4) | (c ^ (n & 15))] = ((const uint4*)Wt16)[idx];
    }
    if (x_fp32) {
        const float4* X4 = (const float4*)Xv;
        for (int idx = tid; idx < MT * 16; idx += 256) {
            int n = idx >> 4, c = idx & 15;
            int row = row0 + n;
            uint4 o = make_uint4(0, 0, 0, 0);
            if (row < N) {
                float4 f0 = X4[(size_t)row * 32 + c * 2];
                float4 f1 = X4[(size_t)row * 32 + c * 2 + 1];
                o.x = bf16rne(f0.x) | (bf16rne(f0.y) << 16);
                o.y = bf16rne(f0.z) | (bf16rne(f0.w) << 16);
                o.z = bf16rne(f1.x) | (bf16rne(f1.y) << 16);
                o.w = bf16rne(f1.z) | (bf16rne(f1.w) << 16);
            }
            XsU[(n << 4) | (c ^ (n & 15))] = o;
        }
    } else {
        const uint4* X16 = (const uint4*)Xv;
        for (int idx = tid; idx < MT * 16; idx += 256) {
            int n = idx >> 4, c = idx & 15;
            int row = row0 + n;
            uint4 o = make_uint4(0, 0, 0, 0);
            if (row < N) o = X16[(size_t)row * 16 + c];
            XsU[(n << 4) | (c ^ (n & 15))] = o;
        }
    }
    __syncthreads();

    int lane = tid & 63, w = tid >> 6;
    int quad = lane >> 4, l16 = lane & 15;
    const bf16x8* WsF = (const bf16x8*)WsU;
    const bf16x8* XsF = (const bf16x8*)XsU;
    f32x4 acc[8];
    #pragma unroll
    for (int i = 0; i < 8; ++i) acc[i] = (f32x4){0.f, 0.f, 0.f, 0.f};

    int arow = w * 16 + l16;
    #pragma unroll
    for (int ks = 0; ks < 4; ++ks) {
        int c = ks * 4 + quad;
        bf16x8 A = XsF[(arow << 4) | (c ^ l16)];
        #pragma unroll
        for (int nt = 0; nt < 8; ++nt) {
            bf16x8 B = WsF[((nt * 16 + l16) << 4) | (c ^ l16)];
            acc[nt] = __builtin_amdgcn_mfma_f32_16x16x32_bf16(A, B, acc[nt], 0, 0, 0);
        }
    }

    // el/er epilogue + block el-max
    float alv[8], arv[8];
    #pragma unroll
    for (int nt = 0; nt < 8; ++nt) { alv[nt] = al[nt * 16 + l16]; arv[nt] = ar[nt * 16 + l16]; }
    float lmax = -1e30f;
    #pragma unroll
    for (int r = 0; r < 4; ++r) {
        float pl = 0.f, pr = 0.f;
        #pragma unroll
        for (int nt = 0; nt < 8; ++nt) { pl += acc[nt][r] * alv[nt]; pr += acc[nt][r] * arv[nt]; }
        #pragma unroll
        for (int o = 1; o < 16; o <<= 1) { pl += __shfl_xor(pl, o); pr += __shfl_xor(pr, o); }
        int row = row0 + w * 16 + quad * 4 + r;
        if (l16 == 0 && row < N) { el[row] = pl; er[row] = pr; }
        lmax = fmaxf(lmax, pl);
    }
    lmax = fmaxf(lmax, __shfl_xor(lmax, 16));
    lmax = fmaxf(lmax, __shfl_xor(lmax, 32));
    if (lane == 0) smax[w] = lmax;

    unsigned short* XsS = (unsigned short*)XsU;
    #pragma unroll
    for (int nt = 0; nt < 8; ++nt)
        #pragma unroll
        for (int r = 0; r < 4; ++r) {
            int lrow = w * 16 + quad * 4 + r;
            int col = nt * 16 + l16;
            int ch = col >> 3;
            int sc = ch ^ (lrow & 15);
            XsS[lrow * 128 + sc * 8 + (col & 7)] = (unsigned short)bf16rne(acc[nt][r]);
        }
    __syncthreads();
    if (tid == 0) {
        float bm = fmaxf(fmaxf(smax[0], smax[1]), fmaxf(smax[2], smax[3]));
        atomicMax(glmax_u, encf(bm));   // one atomic per block, device scope
    }
    for (int idx = tid; idx < MT * 16; idx += 256) {
        int n = idx >> 4, c = idx & 15;
        int row = row0 + n;
        if (row < N) ((uint4*)feat16)[(size_t)row * 16 + c] = XsU[(n << 4) | (c ^ (n & 15))];
    }
}

// ---------------- single-pass edge-softmax + aggregation (global-max shift) --------
// LR(e) = max(e, 0.2e). Packed f32x2 accumulate (v_pk_fma). Unroll 4 edges per
// quarter-wave for MLP (deg ~16 -> ~4 edges per qwave -> one main iteration).

__global__ __launch_bounds__(256) void k_aggregate(
    const unsigned short* __restrict__ feat16, const float* __restrict__ el,
    const float* __restrict__ er, const int* __restrict__ row_ptr,
    const int* __restrict__ csr_src, const float* __restrict__ bias,
    const unsigned* __restrict__ glmax_u, unsigned short* __restrict__ outv, int N) {
    int wid = (blockIdx.x * blockDim.x + threadIdx.x) >> 6;
    int lane = threadIdx.x & 63;
    if (wid >= N) return;
    int beg = row_ptr[wid], end = row_ptr[wid + 1];
    float erd = er[wid];
    float M = decf(glmax_u[0]) + erd;
    M = fmaxf(M, 0.2f * M);

    int qa = lane >> 4, sub = lane & 15;
    const char* fb = (const char*)feat16 + (sub << 4);
    f32x2 a0 = {0.f, 0.f}, a1 = {0.f, 0.f}, a2 = {0.f, 0.f}, a3 = {0.f, 0.f};
    float s = 0.f;
    int j = beg + qa;
    for (; j + 12 < end; j += 16) {
        int sn0 = csr_src[j], sn1 = csr_src[j + 4];
        int sn2 = csr_src[j + 8], sn3 = csr_src[j + 12];
        float t0 = el[sn0] + erd, t1 = el[sn1] + erd;
        float t2 = el[sn2] + erd, t3 = el[sn3] + erd;
        uint4 q0 = *(const uint4*)(fb + ((unsigned)sn0 << 8));
        uint4 q1 = *(const uint4*)(fb + ((unsigned)sn1 << 8));
        uint4 q2 = *(const uint4*)(fb + ((unsigned)sn2 << 8));
        uint4 q3 = *(const uint4*)(fb + ((unsigned)sn3 << 8));
        t0 = fmaxf(t0, 0.2f * t0); t1 = fmaxf(t1, 0.2f * t1);
        t2 = fmaxf(t2, 0.2f * t2); t3 = fmaxf(t3, 0.2f * t3);
        float w0 = __expf(t0 - M), w1 = __expf(t1 - M);
        float w2 = __expf(t2 - M), w3 = __expf(t3 - M);
        s += (w0 + w1) + (w2 + w3);
        f32x2 f;
        f.x = bflo(q0.x); f.y = bfhi(q0.x); a0 += w0 * f;
        f.x = bflo(q0.y); f.y = bfhi(q0.y); a1 += w0 * f;
        f.x = bflo(q0.z); f.y = bfhi(q0.z); a2 += w0 * f;
        f.x = bflo(q0.w); f.y = bfhi(q0.w); a3 += w0 * f;
        f.x = bflo(q1.x); f.y = bfhi(q1.x); a0 += w1 * f;
        f.x = bflo(q1.y); f.y = bfhi(q1.y); a1 += w1 * f;
        f.x = bflo(q1.z); f.y = bfhi(q1.z); a2 += w1 * f;
        f.x = bflo(q1.w); f.y = bfhi(q1.w); a3 += w1 * f;
        f.x = bflo(q2.x); f.y = bfhi(q2.x); a0 += w2 * f;
        f.x = bflo(q2.y); f.y = bfhi(q2.y); a1 += w2 * f;
        f.x = bflo(q2.z); f.y = bfhi(q2.z); a2 += w2 * f;
        f.x = bflo(q2.w); f.y = bfhi(q2.w); a3 += w2 * f;
        f.x = bflo(q3.x); f.y = bfhi(q3.x); a0 += w3 * f;
        f.x = bflo(q3.y); f.y = bfhi(q3.y); a1 += w3 * f;
        f.x = bflo(q3.z); f.y = bfhi(q3.z); a2 += w3 * f;
        f.x = bflo(q3.w); f.y = bfhi(q3.w); a3 += w3 * f;
    }
    for (; j + 4 < end; j += 8) {
        int sn0 = csr_src[j], sn1 = csr_src[j + 4];
        float t0 = el[sn0] + erd, t1 = el[sn1] + erd;
        uint4 q0 = *(const uint4*)(fb + ((unsigned)sn0 << 8));
        uint4 q1 = *(const uint4*)(fb + ((unsigned)sn1 << 8));
        t0 = fmaxf(t0, 0.2f * t0); t1 = fmaxf(t1, 0.2f * t1);
        float w0 = __expf(t0 - M), w1 = __expf(t1 - M);
        s += w0 + w1;
        f32x2 f;
        f.x = bflo(q0.x); f.y = bfhi(q0.x); a0 += w0 * f;
        f.x = bflo(q0.y); f.y = bfhi(q0.y); a1 += w0 * f;
        f.x = bflo(q0.z); f.y = bfhi(q0.z); a2 += w0 * f;
        f.x = bflo(q0.w); f.y = bfhi(q0.w); a3 += w0 * f;
        f.x = bflo(q1.x); f.y = bfhi(q1.x); a0 += w1 * f;
        f.x = bflo(q1.y); f.y = bfhi(q1.y); a1 += w1 * f;
        f.x = bflo(q1.z); f.y = bfhi(q1.z); a2 += w1 * f;
        f.x = bflo(q1.w); f.y = bfhi(q1.w); a3 += w1 * f;
    }
    if (j < end) {
        int sn = csr_src[j];
        float t = el[sn] + erd;
        uint4 q = *(const uint4*)(fb + ((unsigned)sn << 8));
        t = fmaxf(t, 0.2f * t);
        float w = __expf(t - M);
        s += w;
        f32x2 f;
        f.x = bflo(q.x); f.y = bfhi(q.x); a0 += w * f;
        f.x = bflo(q.y); f.y = bfhi(q.y); a1 += w * f;
        f.x = bflo(q.z); f.y = bfhi(q.z); a2 += w * f;
        f.x = bflo(q.w); f.y = bfhi(q.w); a3 += w * f;
    }
    float vr[8] = {a0.x, a0.y, a1.x, a1.y, a2.x, a2.y, a3.x, a3.y};
    #pragma unroll
    for (int c = 0; c < 8; ++c) {
        vr[c] += __shfl_xor(vr[c], 16);
        vr[c] += __shfl_xor(vr[c], 32);
    }
    s += __shfl_xor(s, 16);
    s += __shfl_xor(s, 32);
    float inv = (end > beg) ? 1.f / s : 0.f;
    if (lane < 16) {
        float4 b0 = ((const float4*)bias)[lane * 2];
        float4 b1 = ((const float4*)bias)[lane * 2 + 1];
        float v[8];
        v[0] = fmaxf(vr[0] * inv + b0.x, 0.f);
        v[1] = fmaxf(vr[1] * inv + b0.y, 0.f);
        v[2] = fmaxf(vr[2] * inv + b0.z, 0.f);
        v[3] = fmaxf(vr[3] * inv + b0.w, 0.f);
        v[4] = fmaxf(vr[4] * inv + b1.x, 0.f);
        v[5] = fmaxf(vr[5] * inv + b1.y, 0.f);
        v[6] = fmaxf(vr[6] * inv + b1.z, 0.f);
        v[7] = fmaxf(vr[7] * inv + b1.w, 0.f);
        uint4 pk;
        pk.x = bf16rne(v[0]) | (bf16rne(v[1]) << 16);
        pk.y = bf16rne(v[2]) | (bf16rne(v[3]) << 16);
        pk.z = bf16rne(v[4]) | (bf16rne(v[5]) << 16);
        pk.w = bf16rne(v[6]) | (bf16rne(v[7]) << 16);
        ((uint4*)outv)[(size_t)wid * 16 + lane] = pk;
    }
}

// ---------------- pooling ----------------

__global__ __launch_bounds__(256) void k_pool_partial(const unsigned short* __restrict__ x,
                                                      const int* __restrict__ gs,
                                                      const int* __restrict__ ge,
                                                      float* __restrict__ hg) {
    int g = blockIdx.x, c = blockIdx.y;
    int start = gs[g], last = ge[g];
    if (start > last) return;
    int sub = threadIdx.x & 15;
    int r   = threadIdx.x >> 4;
    const uint4* x4 = (const uint4*)x;
    float acc[8] = {};
    for (int n = start + c * 16 + r; n <= last; n += PCHUNK * 16) {
        uint4 q = x4[(size_t)n * 16 + sub];
        acc[0] += bflo(q.x); acc[1] += bfhi(q.x);
        acc[2] += bflo(q.y); acc[3] += bfhi(q.y);
        acc[4] += bflo(q.z); acc[5] += bfhi(q.z);
        acc[6] += bflo(q.w); acc[7] += bfhi(q.w);
    }
    __shared__ float sm[256][8];
    #pragma unroll
    for (int k = 0; k < 8; ++k) sm[threadIdx.x][k] = acc[k];
    __syncthreads();
    for (int off = 8; off >= 1; off >>= 1) {
        if (r < off) {
            #pragma unroll
            for (int k = 0; k < 8; ++k)
                sm[threadIdx.x][k] += sm[threadIdx.x + off * 16][k];
        }
        __syncthreads();
    }
    if (r == 0) {
        #pragma unroll
        for (int k = 0; k < 8; ++k)
            atomicAdd(&hg[g * D + sub * 8 + k], sm[sub][k]);
    }
}

__global__ void k_final(const float* __restrict__ hg, const int* __restrict__ gs,
                        const int* __restrict__ ge, const float* __restrict__ Wfc,
                        const float* __restrict__ bfc, float* __restrict__ out) {
    int g = threadIdx.x;
    if (g >= NUM_GRAPHS) return;
    int start = gs[g], last = ge[g];
    float cnt = (start <= last) ? (float)(last - start + 1) : 1.f;
    float ic = 1.f / cnt;
    float l0 = bfc[0], l1 = bfc[1];
    for (int d = 0; d < D; d++) {
        float v = hg[g * D + d] * ic;
        l0 += v * Wfc[2 * d];
        l1 += v * Wfc[2 * d + 1];
    }
    float mm = fmaxf(l0, l1);
    float lse = mm + logf(expf(l0 - mm) + expf(l1 - mm));
    out[2 * g] = l0 - lse;
    out[2 * g + 1] = l1 - lse;
}

// ---------------- launch ----------------

extern "C" void kernel_launch(void* const* d_in, const int* in_sizes, int n_in,
                              void* d_out, int out_size, void* d_ws, size_t ws_size,
                              hipStream_t stream) {
    const float* h   = (const float*)d_in[0];
    const int* src   = (const int*)d_in[1];
    const int* dst   = (const int*)d_in[2];
    const int* gid   = (const int*)d_in[3];
    const float* W1  = (const float*)d_in[4];
    const float* al1 = (const float*)d_in[5];
    const float* ar1 = (const float*)d_in[6];
    const float* b1  = (const float*)d_in[7];
    const float* W2  = (const float*)d_in[8];
    const float* al2 = (const float*)d_in[9];
    const float* ar2 = (const float*)d_in[10];
    const float* b2  = (const float*)d_in[11];
    const float* Wfc = (const float*)d_in[12];
    const float* bfc = (const float*)d_in[13];
    float* out = (float*)d_out;

    int N = in_sizes[0] / D;
    int E = in_sizes[1];
    int NB = (N + 127) >> 7;

    char* p = (char*)d_ws;
    unsigned short* feat16  = (unsigned short*)p; p += (size_t)N * D * 2;  // GEMM out
    unsigned short* featAgg = (unsigned short*)p; p += (size_t)N * D * 2;  // agg out (bf16)
    float* el    = (float*)p; p += (size_t)N * 4;
    float* er    = (float*)p; p += (size_t)N * 4;
    int* row_ptr = (int*)p;   p += (size_t)(N + 4) * 4;
    int* csr_src = (int*)p;   p += (size_t)E * 4;
    unsigned* part = (unsigned*)p; p += (size_t)E * 4;
    // zero-region: bhist + glmax + hg (one memset)
    int* bhist   = (int*)p;   p += 1028 * 4;
    unsigned* glmaxu = (unsigned*)p; p += 4 * 4;
    float* hg    = (float*)p; p += NUM_GRAPHS * D * 4;
    size_t zbytes = (char*)p - (char*)bhist;
    int* bbase   = (int*)p;   p += 1028 * 4;
    int* bcur    = (int*)p;   p += 1028 * 4;
    int* gs      = (int*)p;   p += NUM_GRAPHS * 4;
    int* ge      = (int*)p;   p += NUM_GRAPHS * 4;
    unsigned short* Wt1 = (unsigned short*)p; p += D * D * 2;
    unsigned short* Wt2 = (unsigned short*)p; p += D * D * 2;

    int nbN = (N + 255) / 256;
    int nbW = (N * 64 + 255) / 256;
    int nbT = (E + ETILE - 1) / ETILE;
    int gemmB = (N + MT - 1) / MT;

    hipMemsetAsync(bhist, 0, zbytes, stream);                // bhist + glmax + hg
    hipMemsetAsync(gs, 0x7f, NUM_GRAPHS * 4, stream);
    hipMemsetAsync(ge, 0xff, NUM_GRAPHS * 4, stream);

    // front: bucket histogram + weight transpose + graph bounds (one kernel)
    k_front<<<nbT + 16 + nbN, 256, 0, stream>>>(dst, bhist, E, nbT,
                                                W1, W2, Wt1, Wt2, gid, gs, ge, N);
    k_bucket_scan<<<1, 1024, 0, stream>>>(bhist, bbase, bcur, NB, E, row_ptr, N);
    k_partition<<<nbT, 256, 0, stream>>>(src, dst, bcur, part, E);

    // Layer 1: MFMA GEMM (fp32 in) + el/er + glmax, overlapped with bucket->CSR
    k_gemm_mfma_sort<<<gemmB + NB, 256, 0, stream>>>(
        h, 1, Wt1, al1, ar1, feat16, el, er, glmaxu, N, gemmB,
        part, bbase, row_ptr, csr_src);
    k_aggregate<<<nbW, 256, 0, stream>>>(feat16, el, er, row_ptr, csr_src,
                                         b1, glmaxu, featAgg, N);

    // Layer 2: MFMA GEMM (bf16 in), all blocks gemm role
    k_gemm_mfma_sort<<<gemmB, 256, 0, stream>>>(
        featAgg, 0, Wt2, al2, ar2, feat16, el, er, glmaxu + 1, N, gemmB,
        part, bbase, row_ptr, csr_src);
    k_aggregate<<<nbW, 256, 0, stream>>>(feat16, el, er, row_ptr, csr_src,
                                         b2, glmaxu + 1, featAgg, N);

    // Pool + FC + log_softmax
    k_pool_partial<<<dim3(NUM_GRAPHS, PCHUNK), 256, 0, stream>>>(featAgg, gs, ge, hg);
    k_final<<<1, 64, 0, stream>>>(hg, gs, ge, Wfc, bfc, out);
}